// Round 1
// baseline (1083.075 us; speedup 1.0000x reference)
//
#include <hip/hip_runtime.h>

typedef unsigned short u16;
typedef unsigned int   u32;

typedef __bf16 bf16_t;
typedef bf16_t bf16x8 __attribute__((ext_vector_type(8)));
typedef float  f32x4  __attribute__((ext_vector_type(4)));
typedef u16    u16x8  __attribute__((ext_vector_type(8)));

__device__ __forceinline__ float bf2f(u16 u) { return __uint_as_float(((u32)u) << 16); }
__device__ __forceinline__ u16 f2bf(float f) {
  u32 u = __float_as_uint(f);
  u32 r = u + 0x7fffu + ((u >> 16) & 1u);
  return (u16)(r >> 16);
}
__device__ __forceinline__ float fast_exp2(float x) { return __builtin_amdgcn_exp2f(x); }

__device__ __forceinline__ void gload_lds16(const u16* g, u16* l) {
  __builtin_amdgcn_global_load_lds(
      (const __attribute__((address_space(1))) void*)g,
      (__attribute__((address_space(3))) void*)l,
      16, 0, 0);
}

// ---------------- cast f32 -> bf16 (vectorized: 8 elems/thread) ----------------
__global__ void k_cast_bf16v(const float* __restrict__ in, u16* __restrict__ out, int n8) {
  int i = blockIdx.x * blockDim.x + threadIdx.x;
  int stride = gridDim.x * blockDim.x;
  for (; i < n8; i += stride) {
    const f32x4* p = (const f32x4*)(in + (size_t)i * 8);
    f32x4 a = p[0], b = p[1];
    u16x8 o;
    o[0] = f2bf(a[0]); o[1] = f2bf(a[1]); o[2] = f2bf(a[2]); o[3] = f2bf(a[3]);
    o[4] = f2bf(b[0]); o[5] = f2bf(b[1]); o[6] = f2bf(b[2]); o[7] = f2bf(b[3]);
    *(u16x8*)(out + (size_t)i * 8) = o;
  }
}

// ---------------- small GEMM (64x64 tile) for N=256 cases ----------------
#define GBM 64
#define GBN 64
#define GBK 64

__global__ __launch_bounds__(256) void k_gemm_bt(
    const u16* __restrict__ A, const u16* __restrict__ B, float* __restrict__ C,
    int M, int N, int K, float alpha, int beta) {
  __shared__ u16 As[GBM][GBK + 8];
  __shared__ u16 Bs[GBN][GBK + 8];
  const int tid   = threadIdx.x;
  const int lane  = tid & 63;
  const int w     = tid >> 6;
  const int wm    = (w >> 1) * 32;
  const int wn    = (w & 1) * 32;
  const int row16 = lane & 15;
  const int quad  = lane >> 4;
  const int m0 = blockIdx.y * GBM;
  const int n0 = blockIdx.x * GBN;
  const int ldr = tid >> 2;
  const int ldc = (tid & 3) * 16;

  f32x4 acc[2][2] = {};

  for (int k0 = 0; k0 < K; k0 += GBK) {
    const u16* ga = A + (size_t)(m0 + ldr) * K + (k0 + ldc);
    const u16* gb = B + (size_t)(n0 + ldr) * K + (k0 + ldc);
    u16x8 a0 = *(const u16x8*)ga;
    u16x8 a1 = *(const u16x8*)(ga + 8);
    u16x8 b0 = *(const u16x8*)gb;
    u16x8 b1 = *(const u16x8*)(gb + 8);
    __syncthreads();
    *(u16x8*)&As[ldr][ldc]     = a0;
    *(u16x8*)&As[ldr][ldc + 8] = a1;
    *(u16x8*)&Bs[ldr][ldc]     = b0;
    *(u16x8*)&Bs[ldr][ldc + 8] = b1;
    __syncthreads();
#pragma unroll
    for (int kk = 0; kk < GBK; kk += 32) {
      bf16x8 af0 = *(const bf16x8*)&As[wm + row16][kk + quad * 8];
      bf16x8 af1 = *(const bf16x8*)&As[wm + 16 + row16][kk + quad * 8];
      bf16x8 bg0 = *(const bf16x8*)&Bs[wn + row16][kk + quad * 8];
      bf16x8 bg1 = *(const bf16x8*)&Bs[wn + 16 + row16][kk + quad * 8];
      acc[0][0] = __builtin_amdgcn_mfma_f32_16x16x32_bf16(af0, bg0, acc[0][0], 0, 0, 0);
      acc[0][1] = __builtin_amdgcn_mfma_f32_16x16x32_bf16(af0, bg1, acc[0][1], 0, 0, 0);
      acc[1][0] = __builtin_amdgcn_mfma_f32_16x16x32_bf16(af1, bg0, acc[1][0], 0, 0, 0);
      acc[1][1] = __builtin_amdgcn_mfma_f32_16x16x32_bf16(af1, bg1, acc[1][1], 0, 0, 0);
    }
  }
#pragma unroll
  for (int tm = 0; tm < 2; ++tm)
#pragma unroll
    for (int tn = 0; tn < 2; ++tn) {
      int gm = m0 + wm + tm * 16 + quad * 4;
      int gn = n0 + wn + tn * 16 + row16;
#pragma unroll
      for (int r = 0; r < 4; ++r) {
        size_t idx = (size_t)(gm + r) * N + gn;
        float v = alpha * acc[tm][tn][r];
        if (beta) v += C[idx];
        C[idx] = v;
      }
    }
}

// ---------------- m97-structure GEMM: 128x128 tile, BK=64, global_load_lds ----------------
// C(MxN) = alpha * A(MxK) @ B(NxK)^T + beta*C.  Requires M%128==0, N%128==0, K%64==0.
// LDS layout is LINEAR [128][64] (no pad) -- required by global_load_lds lane mapping:
// chunk (w*4+i) covers rows [(w*4+i)*8, +8); lane l -> row +(l>>3), cols (l&7)*8..+8.
#define TBM 128
#define TBN 128
#define TBK 64

__global__ __launch_bounds__(256) void k_gemm_bt128(
    const u16* __restrict__ A, const u16* __restrict__ B, float* __restrict__ C,
    int M, int N, int K, float alpha, int beta) {
  __shared__ u16 As[TBM * TBK];
  __shared__ u16 Bs[TBN * TBK];
  const int tid   = threadIdx.x;
  const int lane  = tid & 63;
  const int w     = tid >> 6;   // 0..3
  const int wr    = w >> 1;     // wave row (0..1) -> 64 rows
  const int wc    = w & 1;      // wave col (0..1) -> 64 cols
  const int row16 = lane & 15;
  const int quad  = lane >> 4;
  const int m0 = blockIdx.y * TBM;
  const int n0 = blockIdx.x * TBN;

  const int sRow = lane >> 3;        // 0..7 within an 8-row chunk
  const int sCol = (lane & 7) * 8;   // 0,8,...,56

  f32x4 acc[4][4] = {};

  for (int k0 = 0; k0 < K; k0 += TBK) {
    __syncthreads();  // previous tile fully consumed (also drains prior vmcnt)
#pragma unroll
    for (int i = 0; i < 4; ++i) {
      const int chunk = w * 4 + i;              // 0..15
      const int rr = chunk * 8 + sRow;          // 0..127
      gload_lds16(A + (size_t)(m0 + rr) * K + k0 + sCol, &As[chunk * 512]);
      gload_lds16(B + (size_t)(n0 + rr) * K + k0 + sCol, &Bs[chunk * 512]);
    }
    __syncthreads();  // drains vmcnt(0) -> tile resident in LDS
#pragma unroll
    for (int kk = 0; kk < TBK; kk += 32) {
      bf16x8 af[4], bg[4];
#pragma unroll
      for (int m = 0; m < 4; ++m)
        af[m] = *(const bf16x8*)&As[(wr * 64 + m * 16 + row16) * TBK + kk + quad * 8];
#pragma unroll
      for (int n = 0; n < 4; ++n)
        bg[n] = *(const bf16x8*)&Bs[(wc * 64 + n * 16 + row16) * TBK + kk + quad * 8];
#pragma unroll
      for (int m = 0; m < 4; ++m)
#pragma unroll
        for (int n = 0; n < 4; ++n)
          acc[m][n] = __builtin_amdgcn_mfma_f32_16x16x32_bf16(af[m], bg[n], acc[m][n], 0, 0, 0);
    }
  }

#pragma unroll
  for (int m = 0; m < 4; ++m) {
    int gm = m0 + wr * 64 + m * 16 + quad * 4;
#pragma unroll
    for (int n = 0; n < 4; ++n) {
      int gn = n0 + wc * 64 + n * 16 + row16;
#pragma unroll
      for (int r = 0; r < 4; ++r) {
        size_t idx = (size_t)(gm + r) * N + gn;
        float v = alpha * acc[m][n][r];
        if (beta) v += C[idx];
        C[idx] = v;
      }
    }
  }
}

// ---------------- RoPE + split q,k (v handled by k_vtrans) ----------------
__global__ void k_rope_split(const float* __restrict__ qkv, const int* __restrict__ pos_ids,
                             u16* __restrict__ qb, u16* __restrict__ kb) {
  const int r  = blockIdx.x;   // 0..4095
  const int hh = blockIdx.y;   // 0..31: 0-23 q, 24-31 k
  const int d  = threadIdx.x;  // 0..127
  const float pos = (float)pos_ids[r];
  const float* src;
  if (hh < 24) src = qkv + (size_t)r * 5120 + hh * 128;
  else         src = qkv + (size_t)r * 5120 + 3072 + (hh - 24) * 128;
  float x = src[d];
  float outv;
  if (d >= 96) {
    outv = x;
  } else {
    int j = (d < 48) ? d : d - 48;
    float invf = powf(10000.0f, -(float)j * (1.0f / 48.0f));
    float e = pos * invf;
    float c = cosf(e), sn = sinf(e);
    if (d < 48) outv = x * c - src[d + 48] * sn;
    else        outv = x * c + src[d - 48] * sn;
  }
  u16 o = f2bf(outv);
  if (hh < 24) qb[((size_t)r * 24 + hh) * 128 + d] = o;
  else         kb[((size_t)r * 8 + (hh - 24)) * 128 + d] = o;
}

// ---------------- V transpose: qkv f32 -> vtg bf16 [b][kvh][d][key] ----------------
__global__ void k_vtrans(const float* __restrict__ qkv, u16* __restrict__ vtg) {
  const int d  = threadIdx.x;  // 0..127
  const int kg = blockIdx.x;   // 0..255: 8-key group
  const int bk = blockIdx.y;   // 0..15: b*8 + kvh
  const int b = bk >> 3, kvh = bk & 7;
  const float* src = qkv + (size_t)(b * 2048 + kg * 8) * 5120 + 4096 + kvh * 128 + d;
  u16x8 pack;
#pragma unroll
  for (int t = 0; t < 8; ++t) pack[t] = f2bf(src[(size_t)t * 5120]);
  *(u16x8*)(vtg + ((size_t)bk * 128 + d) * 2048 + kg * 8) = pack;
}

// ---------------- MFMA flash attention (causal, GQA 24q/8kv, D=128) ----------------
#define KS_STRIDE 136  // 128 + 8 (u16)
#define VT_STRIDE 72   // 64 + 8
#define PS_STRIDE 72   // 64 + 8

__global__ __launch_bounds__(256) void k_attn_mfma(
    const u16* __restrict__ qb, const u16* __restrict__ kb, const u16* __restrict__ vtg,
    u16* __restrict__ attnb) {
  __shared__ u16 Ks[64 * KS_STRIDE];      // [key][d]
  __shared__ u16 Vt[128 * VT_STRIDE];     // [d][key]
  __shared__ u16 Ps[4 * 16 * PS_STRIDE];  // per-wave [m][key]

  const int tid   = threadIdx.x;
  const int lane  = tid & 63;
  const int w     = tid >> 6;
  const int row16 = lane & 15;
  const int quad  = lane >> 4;
  const int qt  = (int)gridDim.x - 1 - (int)blockIdx.x;  // heavy tiles first
  const int bh  = blockIdx.y;
  const int b   = bh / 24;
  const int h   = bh % 24;
  const int kvh = h / 3;
  const int q0  = qt * 64;

  const u16* qbase = qb + (((size_t)(b * 2048 + q0 + w * 16 + row16)) * 24 + h) * 128;
  bf16x8 qfrag[4];
#pragma unroll
  for (int kk = 0; kk < 4; ++kk) qfrag[kk] = *(const bf16x8*)(qbase + kk * 32 + quad * 8);

  const u16* kbbase = kb + ((size_t)(b * 2048) * 8 + kvh) * 128;
  const u16* vtbase = vtg + (size_t)(b * 8 + kvh) * 128 * 2048;

  f32x4 o[8] = {};
  float mrow[4] = {-INFINITY, -INFINITY, -INFINITY, -INFINITY};
  float lrow[4] = {0.f, 0.f, 0.f, 0.f};
  const float C1 = 0.08838834764831845f * 1.4426950408889634f;  // SCALE * log2(e)

  for (int t = 0; t <= qt; ++t) {
    const int kb0 = t * 64;
    __syncthreads();
#pragma unroll
    for (int i = 0; i < 4; ++i) {
      int c = tid + i * 256;
      int kk = c >> 4, d8 = (c & 15) * 8;
      *(u16x8*)&Ks[kk * KS_STRIDE + d8] =
          *(const u16x8*)(kbbase + (size_t)(kb0 + kk) * (8 * 128) + d8);
    }
#pragma unroll
    for (int i = 0; i < 4; ++i) {
      int c = tid + i * 256;
      int d = c >> 3, k8 = (c & 7) * 8;
      *(u16x8*)&Vt[d * VT_STRIDE + k8] =
          *(const u16x8*)(vtbase + (size_t)d * 2048 + kb0 + k8);
    }
    __syncthreads();

    f32x4 s[4] = {};
#pragma unroll
    for (int kk = 0; kk < 4; ++kk) {
#pragma unroll
      for (int nt = 0; nt < 4; ++nt) {
        bf16x8 bfr = *(const bf16x8*)&Ks[(nt * 16 + row16) * KS_STRIDE + kk * 32 + quad * 8];
        s[nt] = __builtin_amdgcn_mfma_f32_16x16x32_bf16(qfrag[kk], bfr, s[nt], 0, 0, 0);
      }
    }

    if (t == qt) {
#pragma unroll
      for (int nt = 0; nt < 4; ++nt) {
        int col = kb0 + nt * 16 + row16;
#pragma unroll
        for (int r = 0; r < 4; ++r) {
          int row = q0 + w * 16 + quad * 4 + r;
          if (col > row) s[nt][r] = -INFINITY;
        }
      }
    }

#pragma unroll
    for (int r = 0; r < 4; ++r) {
      float mx = fmaxf(fmaxf(s[0][r], s[1][r]), fmaxf(s[2][r], s[3][r]));
#pragma unroll
      for (int off = 1; off < 16; off <<= 1) mx = fmaxf(mx, __shfl_xor(mx, off));
      float mnew = fmaxf(mrow[r], mx);
      float alpha = fast_exp2((mrow[r] - mnew) * C1);
      mrow[r] = mnew;
      float rs = 0.f;
#pragma unroll
      for (int nt = 0; nt < 4; ++nt) {
        float p = fast_exp2((s[nt][r] - mnew) * C1);
        s[nt][r] = p;
        rs += p;
      }
#pragma unroll
      for (int off = 1; off < 16; off <<= 1) rs += __shfl_xor(rs, off);
      lrow[r] = lrow[r] * alpha + rs;
#pragma unroll
      for (int dt = 0; dt < 8; ++dt) o[dt][r] *= alpha;
    }

#pragma unroll
    for (int nt = 0; nt < 4; ++nt)
#pragma unroll
      for (int r = 0; r < 4; ++r)
        Ps[(w * 16 + quad * 4 + r) * PS_STRIDE + nt * 16 + row16] = f2bf(s[nt][r]);

#pragma unroll
    for (int kk2 = 0; kk2 < 2; ++kk2) {
      bf16x8 pa = *(const bf16x8*)&Ps[(w * 16 + row16) * PS_STRIDE + kk2 * 32 + quad * 8];
#pragma unroll
      for (int dt = 0; dt < 8; ++dt) {
        bf16x8 vfr = *(const bf16x8*)&Vt[(dt * 16 + row16) * VT_STRIDE + kk2 * 32 + quad * 8];
        o[dt] = __builtin_amdgcn_mfma_f32_16x16x32_bf16(pa, vfr, o[dt], 0, 0, 0);
      }
    }
  }

#pragma unroll
  for (int r = 0; r < 4; ++r) {
    float inv = 1.0f / lrow[r];
    int row = q0 + w * 16 + quad * 4 + r;
    size_t obase = ((size_t)(b * 2048 + row)) * 3072 + (size_t)h * 128;
#pragma unroll
    for (int dt = 0; dt < 8; ++dt)
      attnb[obase + dt * 16 + row16] = f2bf(o[dt][r] * inv);
  }
}

// ---------------- workspace layout (bytes) ----------------
#define SZ_XB     ((size_t)4096 * 3072 * 2)
#define SZ_WQKVB  ((size_t)5120 * 3072 * 2)
#define SZ_AQKVB  ((size_t)256 * 3072 * 2)
#define SZ_BQKVB  ((size_t)5120 * 256 * 2)
#define SZ_WOB    ((size_t)3072 * 3072 * 2)
#define SZ_AOB    ((size_t)256 * 3072 * 2)
#define SZ_BOB    ((size_t)3072 * 256 * 2)
#define SZ_QKV    ((size_t)4096 * 5120 * 4)
#define SZ_TA     ((size_t)4096 * 256 * 4)
#define SZ_TAB    ((size_t)4096 * 256 * 2)

#define OFF_XB    ((size_t)0)
#define OFF_WQKVB (OFF_XB + SZ_XB)
#define OFF_AQKVB (OFF_WQKVB + SZ_WQKVB)
#define OFF_BQKVB (OFF_AQKVB + SZ_AQKVB)
#define OFF_WOB   (OFF_BQKVB + SZ_BQKVB)
#define OFF_AOB   (OFF_WOB + SZ_WOB)
#define OFF_BOB   (OFF_AOB + SZ_AOB)
#define OFF_QKV   (OFF_BOB + SZ_BOB)
#define OFF_TA    (OFF_QKV + SZ_QKV)
#define OFF_TAB   (OFF_TA + SZ_TA)
#define OFF_QB    OFF_XB
#define OFF_KB    OFF_WQKVB
#define OFF_VTG   (OFF_WQKVB + (size_t)8388608)
#define OFF_ATTNB OFF_QKV
#define OFF_TO    (OFF_QKV + (size_t)25165824)
#define OFF_TOB   (OFF_TO + (size_t)4194304)

static inline void launch_cast(const float* in, u16* out, int n, hipStream_t s) {
  int n8 = n >> 3;  // all sizes here are multiples of 8
  int blocks = (n8 + 255) / 256;
  if (blocks > 2048) blocks = 2048;
  k_cast_bf16v<<<blocks, 256, 0, s>>>(in, out, n8);
}

extern "C" void kernel_launch(void* const* d_in, const int* in_sizes, int n_in,
                              void* d_out, int out_size, void* d_ws, size_t ws_size,
                              hipStream_t stream) {
  const float* x    = (const float*)d_in[0];
  const float* Wqkv = (const float*)d_in[1];
  const float* Aqkv = (const float*)d_in[2];
  const float* Bqkv = (const float*)d_in[3];
  const float* Wo   = (const float*)d_in[4];
  const float* Ao   = (const float*)d_in[5];
  const float* Bo   = (const float*)d_in[6];
  const int*   pos  = (const int*)d_in[7];
  float* out = (float*)d_out;
  char* ws = (char*)d_ws;

  u16* xb    = (u16*)(ws + OFF_XB);
  u16* wqkvb = (u16*)(ws + OFF_WQKVB);
  u16* aqkvb = (u16*)(ws + OFF_AQKVB);
  u16* bqkvb = (u16*)(ws + OFF_BQKVB);
  u16* wob   = (u16*)(ws + OFF_WOB);
  u16* aob   = (u16*)(ws + OFF_AOB);
  u16* bob   = (u16*)(ws + OFF_BOB);
  float* qkv = (float*)(ws + OFF_QKV);
  float* tA  = (float*)(ws + OFF_TA);
  u16* tab   = (u16*)(ws + OFF_TAB);
  u16* qb    = (u16*)(ws + OFF_QB);
  u16* kb    = (u16*)(ws + OFF_KB);
  u16* vtg   = (u16*)(ws + OFF_VTG);
  u16* attnb = (u16*)(ws + OFF_ATTNB);
  float* tO  = (float*)(ws + OFF_TO);
  u16* tob   = (u16*)(ws + OFF_TOB);

  // 1) casts
  launch_cast(x,    xb,    4096 * 3072, stream);
  launch_cast(Wqkv, wqkvb, 5120 * 3072, stream);
  launch_cast(Aqkv, aqkvb, 256 * 3072,  stream);
  launch_cast(Bqkv, bqkvb, 5120 * 256,  stream);
  launch_cast(Wo,   wob,   3072 * 3072, stream);
  launch_cast(Ao,   aob,   256 * 3072,  stream);
  launch_cast(Bo,   bob,   3072 * 256,  stream);

  // 2) qkv = x @ Wqkv^T + 2 * (x @ Aqkv^T) @ Bqkv^T
  k_gemm_bt128<<<dim3(5120 / 128, 4096 / 128), 256, 0, stream>>>(xb, wqkvb, qkv, 4096, 5120, 3072, 1.f, 0);
  k_gemm_bt<<<dim3(256 / 64, 4096 / 64), 256, 0, stream>>>(xb, aqkvb, tA, 4096, 256, 3072, 1.f, 0);
  launch_cast(tA, tab, 4096 * 256, stream);
  k_gemm_bt128<<<dim3(5120 / 128, 4096 / 128), 256, 0, stream>>>(tab, bqkvb, qkv, 4096, 5120, 256, 2.0f, 1);

  // 3) rope+split q,k ; transpose-cast v
  k_rope_split<<<dim3(4096, 32), 128, 0, stream>>>(qkv, pos, qb, kb);
  k_vtrans<<<dim3(256, 16), 128, 0, stream>>>(qkv, vtg);

  // 4) MFMA flash attention
  k_attn_mfma<<<dim3(32, 48), 256, 0, stream>>>(qb, kb, vtg, attnb);

  // 5) out = attn @ Wo^T + 2 * (attn @ Ao^T) @ Bo^T
  k_gemm_bt128<<<dim3(3072 / 128, 4096 / 128), 256, 0, stream>>>(attnb, wob, out, 4096, 3072, 3072, 1.f, 0);
  k_gemm_bt<<<dim3(256 / 64, 4096 / 64), 256, 0, stream>>>(attnb, aob, tO, 4096, 256, 3072, 1.f, 0);
  launch_cast(tO, tob, 4096 * 256, stream);
  k_gemm_bt128<<<dim3(3072 / 128, 4096 / 128), 256, 0, stream>>>(tob, bob, out, 4096, 3072, 256, 2.0f, 1);
}

// Round 2
// 930.032 us; speedup vs baseline: 1.1646x; 1.1646x over previous
//
#include <hip/hip_runtime.h>

typedef unsigned short u16;
typedef unsigned int   u32;

typedef __bf16 bf16_t;
typedef bf16_t bf16x8 __attribute__((ext_vector_type(8)));
typedef float  f32x4  __attribute__((ext_vector_type(4)));
typedef u16    u16x8  __attribute__((ext_vector_type(8)));

__device__ __forceinline__ float bf2f(u16 u) { return __uint_as_float(((u32)u) << 16); }
__device__ __forceinline__ u16 f2bf(float f) {
  u32 u = __float_as_uint(f);
  u32 r = u + 0x7fffu + ((u >> 16) & 1u);
  return (u16)(r >> 16);
}
__device__ __forceinline__ float fast_exp2(float x) { return __builtin_amdgcn_exp2f(x); }

__device__ __forceinline__ void gload_lds16(const u16* g, u16* l) {
  __builtin_amdgcn_global_load_lds(
      (const __attribute__((address_space(1))) void*)g,
      (__attribute__((address_space(3))) void*)l,
      16, 0, 0);
}

// ---------------- cast f32 -> bf16 (vectorized: 8 elems/thread) ----------------
__global__ void k_cast_bf16v(const float* __restrict__ in, u16* __restrict__ out, int n8) {
  int i = blockIdx.x * blockDim.x + threadIdx.x;
  int stride = gridDim.x * blockDim.x;
  for (; i < n8; i += stride) {
    const f32x4* p = (const f32x4*)(in + (size_t)i * 8);
    f32x4 a = p[0], b = p[1];
    u16x8 o;
    o[0] = f2bf(a[0]); o[1] = f2bf(a[1]); o[2] = f2bf(a[2]); o[3] = f2bf(a[3]);
    o[4] = f2bf(b[0]); o[5] = f2bf(b[1]); o[6] = f2bf(b[2]); o[7] = f2bf(b[3]);
    *(u16x8*)(out + (size_t)i * 8) = o;
  }
}

// ---------------- small GEMM (64x64 tile) for N=256 / K=256 cases ----------------
#define GBM 64
#define GBN 64
#define GBK 64

__global__ __launch_bounds__(256) void k_gemm_bt(
    const u16* __restrict__ A, const u16* __restrict__ B, float* __restrict__ C,
    int M, int N, int K, float alpha, int beta) {
  __shared__ u16 As[GBM][GBK + 8];
  __shared__ u16 Bs[GBN][GBK + 8];
  const int tid   = threadIdx.x;
  const int lane  = tid & 63;
  const int w     = tid >> 6;
  const int wm    = (w >> 1) * 32;
  const int wn    = (w & 1) * 32;
  const int row16 = lane & 15;
  const int quad  = lane >> 4;
  const int m0 = blockIdx.y * GBM;
  const int n0 = blockIdx.x * GBN;
  const int ldr = tid >> 2;
  const int ldc = (tid & 3) * 16;

  f32x4 acc[2][2] = {};

  for (int k0 = 0; k0 < K; k0 += GBK) {
    const u16* ga = A + (size_t)(m0 + ldr) * K + (k0 + ldc);
    const u16* gb = B + (size_t)(n0 + ldr) * K + (k0 + ldc);
    u16x8 a0 = *(const u16x8*)ga;
    u16x8 a1 = *(const u16x8*)(ga + 8);
    u16x8 b0 = *(const u16x8*)gb;
    u16x8 b1 = *(const u16x8*)(gb + 8);
    __syncthreads();
    *(u16x8*)&As[ldr][ldc]     = a0;
    *(u16x8*)&As[ldr][ldc + 8] = a1;
    *(u16x8*)&Bs[ldr][ldc]     = b0;
    *(u16x8*)&Bs[ldr][ldc + 8] = b1;
    __syncthreads();
#pragma unroll
    for (int kk = 0; kk < GBK; kk += 32) {
      bf16x8 af0 = *(const bf16x8*)&As[wm + row16][kk + quad * 8];
      bf16x8 af1 = *(const bf16x8*)&As[wm + 16 + row16][kk + quad * 8];
      bf16x8 bg0 = *(const bf16x8*)&Bs[wn + row16][kk + quad * 8];
      bf16x8 bg1 = *(const bf16x8*)&Bs[wn + 16 + row16][kk + quad * 8];
      acc[0][0] = __builtin_amdgcn_mfma_f32_16x16x32_bf16(af0, bg0, acc[0][0], 0, 0, 0);
      acc[0][1] = __builtin_amdgcn_mfma_f32_16x16x32_bf16(af0, bg1, acc[0][1], 0, 0, 0);
      acc[1][0] = __builtin_amdgcn_mfma_f32_16x16x32_bf16(af1, bg0, acc[1][0], 0, 0, 0);
      acc[1][1] = __builtin_amdgcn_mfma_f32_16x16x32_bf16(af1, bg1, acc[1][1], 0, 0, 0);
    }
  }
#pragma unroll
  for (int tm = 0; tm < 2; ++tm)
#pragma unroll
    for (int tn = 0; tn < 2; ++tn) {
      int gm = m0 + wm + tm * 16 + quad * 4;
      int gn = n0 + wn + tn * 16 + row16;
#pragma unroll
      for (int r = 0; r < 4; ++r) {
        size_t idx = (size_t)(gm + r) * N + gn;
        float v = alpha * acc[tm][tn][r];
        if (beta) v += C[idx];
        C[idx] = v;
      }
    }
}

// ================= 256x256 8-phase GEMM (m201 template, plain HIP) =================
// C(MxN) = A(MxK) @ B(NxK)^T.  Requires M%256==0, N%256==0, K%64==0, K>=192, grid%8==0.
// 512 threads (8 waves, 2Mx4N), BK=64, LDS 128KiB double-buffered.
// T2 swizzle: linear gload_lds dest + XOR'd global source col + XOR'd ds_read col.
// Half-tile stream (Ah0,Ah1,Bh0,Bh1 per tile) staged 1/phase, 5 phases ahead;
// boundary wait = vmcnt(2) (one half-tile = 2 loads in flight), vmcnt(0) at final.

// stage half-tile H: tile t=H>>2 (buf t&1), slot H&3 (0,1=A halves; 2,3=B halves)
__device__ __forceinline__ void stage_half(
    int H, int nt4,
    const u16* __restrict__ A, const u16* __restrict__ B, int K,
    int m0, int n0, u16* AsB, u16* BsB,
    int w, int rowin, int colsw) {
  if (H >= nt4) return;
  const int t = H >> 2, slot = H & 3;
  const int half = slot & 1;
  const u16* G = (slot < 2) ? A : B;
  const int r0 = (slot < 2) ? m0 : n0;
  u16* lds = ((slot < 2) ? AsB : BsB) + (t & 1) * 16384 + half * 8192;
  const int k0 = t * 64;
#pragma unroll
  for (int i = 0; i < 2; ++i) {
    const int chunk = w * 2 + i;                  // 0..15, wave-uniform
    const int row = half * 128 + chunk * 8 + rowin;
    gload_lds16(G + (size_t)(r0 + row) * K + k0 + colsw, lds + chunk * 512);
  }
}

// swizzled fragment read: row in [0,256), c16 = kk*4+quad (16B slot index)
__device__ __forceinline__ bf16x8 frag_ld(const u16* base, int row, int c16) {
  return *(const bf16x8*)(base + row * 64 + ((c16 ^ (row & 7)) << 3));
}

#define SBAR0() __builtin_amdgcn_sched_barrier(0)
#define HWBAR() __builtin_amdgcn_s_barrier()

template <int RB>
__device__ __forceinline__ void gemm256_group(
    int k, int nt,
    const u16* __restrict__ A, const u16* __restrict__ B, int K,
    int m0, int n0, u16* AsB, u16* BsB,
    int wr, int wc, int row16, int quad, int w, int rowin, int colsw,
    f32x4 (&acc)[8][4]) {
  const u16* Ab = AsB + RB * 16384;
  const u16* Bb = BsB + RB * 16384;
  const int nt4 = nt * 4;
  bf16x8 a0[4][2], a1[4][2], b0[2][2], b1[2][2];

  // ---- phase q0: read A(mh0) 8 + B(np0) 4; stage Ah1(k+1); MFMA (mh0,np0) ----
#pragma unroll
  for (int mf = 0; mf < 4; ++mf)
#pragma unroll
    for (int kk = 0; kk < 2; ++kk)
      a0[mf][kk] = frag_ld(Ab, wr * 128 + mf * 16 + row16, kk * 4 + quad);
#pragma unroll
  for (int nf = 0; nf < 2; ++nf)
#pragma unroll
    for (int kk = 0; kk < 2; ++kk)
      b0[nf][kk] = frag_ld(Bb, wc * 64 + nf * 16 + row16, kk * 4 + quad);
  stage_half(4 * k + 5, nt4, A, B, K, m0, n0, AsB, BsB, w, rowin, colsw);
  SBAR0(); HWBAR(); SBAR0();
  __builtin_amdgcn_s_setprio(1);
#pragma unroll
  for (int mf = 0; mf < 4; ++mf)
#pragma unroll
    for (int nf = 0; nf < 2; ++nf)
#pragma unroll
      for (int kk = 0; kk < 2; ++kk)
        acc[mf][nf] = __builtin_amdgcn_mfma_f32_16x16x32_bf16(a0[mf][kk], b0[nf][kk], acc[mf][nf], 0, 0, 0);
  __builtin_amdgcn_s_setprio(0);
  SBAR0(); HWBAR(); SBAR0();

  // ---- phase q1: read B(np1) 4; stage Bh0(k+1); MFMA (mh0,np1) ----
#pragma unroll
  for (int nf = 0; nf < 2; ++nf)
#pragma unroll
    for (int kk = 0; kk < 2; ++kk)
      b1[nf][kk] = frag_ld(Bb, wc * 64 + 32 + nf * 16 + row16, kk * 4 + quad);
  stage_half(4 * k + 6, nt4, A, B, K, m0, n0, AsB, BsB, w, rowin, colsw);
  SBAR0(); HWBAR(); SBAR0();
  __builtin_amdgcn_s_setprio(1);
#pragma unroll
  for (int mf = 0; mf < 4; ++mf)
#pragma unroll
    for (int nf = 0; nf < 2; ++nf)
#pragma unroll
      for (int kk = 0; kk < 2; ++kk)
        acc[mf][2 + nf] = __builtin_amdgcn_mfma_f32_16x16x32_bf16(a0[mf][kk], b1[nf][kk], acc[mf][2 + nf], 0, 0, 0);
  __builtin_amdgcn_s_setprio(0);
  SBAR0(); HWBAR(); SBAR0();

  // ---- phase q2: read A(mh1) 8; stage Bh1(k+1); MFMA (mh1,np0) ----
#pragma unroll
  for (int mf = 0; mf < 4; ++mf)
#pragma unroll
    for (int kk = 0; kk < 2; ++kk)
      a1[mf][kk] = frag_ld(Ab, wr * 128 + 64 + mf * 16 + row16, kk * 4 + quad);
  stage_half(4 * k + 7, nt4, A, B, K, m0, n0, AsB, BsB, w, rowin, colsw);
  SBAR0(); HWBAR(); SBAR0();
  __builtin_amdgcn_s_setprio(1);
#pragma unroll
  for (int mf = 0; mf < 4; ++mf)
#pragma unroll
    for (int nf = 0; nf < 2; ++nf)
#pragma unroll
      for (int kk = 0; kk < 2; ++kk)
        acc[4 + mf][nf] = __builtin_amdgcn_mfma_f32_16x16x32_bf16(a1[mf][kk], b0[nf][kk], acc[4 + mf][nf], 0, 0, 0);
  __builtin_amdgcn_s_setprio(0);
  SBAR0(); HWBAR(); SBAR0();

  // ---- phase q3: no reads; stage Ah0(k+2); boundary vmcnt; MFMA (mh1,np1) ----
  stage_half(4 * k + 8, nt4, A, B, K, m0, n0, AsB, BsB, w, rowin, colsw);
  SBAR0();
  if (k < nt - 2) { asm volatile("s_waitcnt vmcnt(2)" ::: "memory"); }
  else            { asm volatile("s_waitcnt vmcnt(0)" ::: "memory"); }
  HWBAR(); SBAR0();
  __builtin_amdgcn_s_setprio(1);
#pragma unroll
  for (int mf = 0; mf < 4; ++mf)
#pragma unroll
    for (int nf = 0; nf < 2; ++nf)
#pragma unroll
      for (int kk = 0; kk < 2; ++kk)
        acc[4 + mf][2 + nf] = __builtin_amdgcn_mfma_f32_16x16x32_bf16(a1[mf][kk], b1[nf][kk], acc[4 + mf][2 + nf], 0, 0, 0);
  __builtin_amdgcn_s_setprio(0);
  SBAR0(); HWBAR(); SBAR0();
}

__global__ __launch_bounds__(512, 2) void k_gemm256(
    const u16* __restrict__ A, const u16* __restrict__ B, float* __restrict__ C,
    int M, int N, int K) {
  __shared__ u16 As[2 * 16384];   // 64 KiB: [buf][256 rows][64 cols] swizzled
  __shared__ u16 Bs[2 * 16384];   // 64 KiB

  const int tid   = threadIdx.x;
  const int lane  = tid & 63;
  const int w     = tid >> 6;    // 0..7
  const int wr    = w >> 2;      // 0..1 -> 128 rows
  const int wc    = w & 3;       // 0..3 -> 64 cols
  const int row16 = lane & 15;
  const int quad  = lane >> 4;
  const int rowin = lane >> 3;                       // staging: row within 8-row chunk
  const int colsw = ((lane & 7) ^ (lane >> 3)) << 3; // staging: swizzled source col (u16)

  // T1: bijective XCD swizzle (grid%8==0 here -> simple form)
  const int nwg = (int)gridDim.x;
  const int bid = (int)blockIdx.x;
  const int xcd = bid & 7, rest = bid >> 3;
  const int qq = nwg >> 3, rr = nwg & 7;
  const int wg = (xcd < rr ? xcd * (qq + 1) : rr * (qq + 1) + (xcd - rr) * qq) + rest;
  const int nbx = N >> 8;
  const int m0 = (wg / nbx) << 8;
  const int n0 = (wg % nbx) << 8;

  const int nt = K >> 6;
  f32x4 acc[8][4] = {};

  // prologue: stage H=0..4 (tile0 complete + Ah0 of tile1), wait tile0, barrier
#pragma unroll
  for (int H = 0; H < 5; ++H)
    stage_half(H, nt * 4, A, B, K, m0, n0, As, Bs, w, rowin, colsw);
  asm volatile("s_waitcnt vmcnt(2)" ::: "memory");
  HWBAR(); SBAR0();

  int k = 0;
  for (; k + 1 < nt; k += 2) {
    gemm256_group<0>(k,     nt, A, B, K, m0, n0, As, Bs, wr, wc, row16, quad, w, rowin, colsw, acc);
    gemm256_group<1>(k + 1, nt, A, B, K, m0, n0, As, Bs, wr, wc, row16, quad, w, rowin, colsw, acc);
  }
  if (k < nt)
    gemm256_group<0>(k, nt, A, B, K, m0, n0, As, Bs, wr, wc, row16, quad, w, rowin, colsw, acc);

  // epilogue: C = acc (alpha=1, beta=0 by contract)
#pragma unroll
  for (int mi = 0; mi < 8; ++mi) {
    const int gm = m0 + wr * 128 + mi * 16 + quad * 4;
#pragma unroll
    for (int nj = 0; nj < 4; ++nj) {
      const int gn = n0 + wc * 64 + nj * 16 + row16;
#pragma unroll
      for (int r = 0; r < 4; ++r)
        C[(size_t)(gm + r) * N + gn] = acc[mi][nj][r];
    }
  }
}

// ---------------- RoPE + split q,k (v handled by k_vtrans) ----------------
__global__ void k_rope_split(const float* __restrict__ qkv, const int* __restrict__ pos_ids,
                             u16* __restrict__ qb, u16* __restrict__ kb) {
  const int r  = blockIdx.x;
  const int hh = blockIdx.y;
  const int d  = threadIdx.x;
  const float pos = (float)pos_ids[r];
  const float* src;
  if (hh < 24) src = qkv + (size_t)r * 5120 + hh * 128;
  else         src = qkv + (size_t)r * 5120 + 3072 + (hh - 24) * 128;
  float x = src[d];
  float outv;
  if (d >= 96) {
    outv = x;
  } else {
    int j = (d < 48) ? d : d - 48;
    float invf = powf(10000.0f, -(float)j * (1.0f / 48.0f));
    float e = pos * invf;
    float c = cosf(e), sn = sinf(e);
    if (d < 48) outv = x * c - src[d + 48] * sn;
    else        outv = x * c + src[d - 48] * sn;
  }
  u16 o = f2bf(outv);
  if (hh < 24) qb[((size_t)r * 24 + hh) * 128 + d] = o;
  else         kb[((size_t)r * 8 + (hh - 24)) * 128 + d] = o;
}

// ---------------- V transpose: qkv f32 -> vtg bf16 [b][kvh][d][key] ----------------
__global__ void k_vtrans(const float* __restrict__ qkv, u16* __restrict__ vtg) {
  const int d  = threadIdx.x;
  const int kg = blockIdx.x;
  const int bk = blockIdx.y;
  const int b = bk >> 3, kvh = bk & 7;
  const float* src = qkv + (size_t)(b * 2048 + kg * 8) * 5120 + 4096 + kvh * 128 + d;
  u16x8 pack;
#pragma unroll
  for (int t = 0; t < 8; ++t) pack[t] = f2bf(src[(size_t)t * 5120]);
  *(u16x8*)(vtg + ((size_t)bk * 128 + d) * 2048 + kg * 8) = pack;
}

// ---------------- MFMA flash attention (causal, GQA 24q/8kv, D=128) ----------------
#define KS_STRIDE 136
#define VT_STRIDE 72
#define PS_STRIDE 72

__global__ __launch_bounds__(256) void k_attn_mfma(
    const u16* __restrict__ qb, const u16* __restrict__ kb, const u16* __restrict__ vtg,
    u16* __restrict__ attnb) {
  __shared__ u16 Ks[64 * KS_STRIDE];
  __shared__ u16 Vt[128 * VT_STRIDE];
  __shared__ u16 Ps[4 * 16 * PS_STRIDE];

  const int tid   = threadIdx.x;
  const int lane  = tid & 63;
  const int w     = tid >> 6;
  const int row16 = lane & 15;
  const int quad  = lane >> 4;
  const int qt  = (int)gridDim.x - 1 - (int)blockIdx.x;
  const int bh  = blockIdx.y;
  const int b   = bh / 24;
  const int h   = bh % 24;
  const int kvh = h / 3;
  const int q0  = qt * 64;

  const u16* qbase = qb + (((size_t)(b * 2048 + q0 + w * 16 + row16)) * 24 + h) * 128;
  bf16x8 qfrag[4];
#pragma unroll
  for (int kk = 0; kk < 4; ++kk) qfrag[kk] = *(const bf16x8*)(qbase + kk * 32 + quad * 8);

  const u16* kbbase = kb + ((size_t)(b * 2048) * 8 + kvh) * 128;
  const u16* vtbase = vtg + (size_t)(b * 8 + kvh) * 128 * 2048;

  f32x4 o[8] = {};
  float mrow[4] = {-INFINITY, -INFINITY, -INFINITY, -INFINITY};
  float lrow[4] = {0.f, 0.f, 0.f, 0.f};
  const float C1 = 0.08838834764831845f * 1.4426950408889634f;

  for (int t = 0; t <= qt; ++t) {
    const int kb0 = t * 64;
    __syncthreads();
#pragma unroll
    for (int i = 0; i < 4; ++i) {
      int c = tid + i * 256;
      int kk = c >> 4, d8 = (c & 15) * 8;
      *(u16x8*)&Ks[kk * KS_STRIDE + d8] =
          *(const u16x8*)(kbbase + (size_t)(kb0 + kk) * (8 * 128) + d8);
    }
#pragma unroll
    for (int i = 0; i < 4; ++i) {
      int c = tid + i * 256;
      int d = c >> 3, k8 = (c & 7) * 8;
      *(u16x8*)&Vt[d * VT_STRIDE + k8] =
          *(const u16x8*)(vtbase + (size_t)d * 2048 + kb0 + k8);
    }
    __syncthreads();

    f32x4 s[4] = {};
#pragma unroll
    for (int kk = 0; kk < 4; ++kk) {
#pragma unroll
      for (int nt = 0; nt < 4; ++nt) {
        bf16x8 bfr = *(const bf16x8*)&Ks[(nt * 16 + row16) * KS_STRIDE + kk * 32 + quad * 8];
        s[nt] = __builtin_amdgcn_mfma_f32_16x16x32_bf16(qfrag[kk], bfr, s[nt], 0, 0, 0);
      }
    }

    if (t == qt) {
#pragma unroll
      for (int nt = 0; nt < 4; ++nt) {
        int col = kb0 + nt * 16 + row16;
#pragma unroll
        for (int r = 0; r < 4; ++r) {
          int row = q0 + w * 16 + quad * 4 + r;
          if (col > row) s[nt][r] = -INFINITY;
        }
      }
    }

#pragma unroll
    for (int r = 0; r < 4; ++r) {
      float mx = fmaxf(fmaxf(s[0][r], s[1][r]), fmaxf(s[2][r], s[3][r]));
#pragma unroll
      for (int off = 1; off < 16; off <<= 1) mx = fmaxf(mx, __shfl_xor(mx, off));
      float mnew = fmaxf(mrow[r], mx);
      float alpha = fast_exp2((mrow[r] - mnew) * C1);
      mrow[r] = mnew;
      float rs = 0.f;
#pragma unroll
      for (int nt = 0; nt < 4; ++nt) {
        float p = fast_exp2((s[nt][r] - mnew) * C1);
        s[nt][r] = p;
        rs += p;
      }
#pragma unroll
      for (int off = 1; off < 16; off <<= 1) rs += __shfl_xor(rs, off);
      lrow[r] = lrow[r] * alpha + rs;
#pragma unroll
      for (int dt = 0; dt < 8; ++dt) o[dt][r] *= alpha;
    }

#pragma unroll
    for (int nt = 0; nt < 4; ++nt)
#pragma unroll
      for (int r = 0; r < 4; ++r)
        Ps[(w * 16 + quad * 4 + r) * PS_STRIDE + nt * 16 + row16] = f2bf(s[nt][r]);

#pragma unroll
    for (int kk2 = 0; kk2 < 2; ++kk2) {
      bf16x8 pa = *(const bf16x8*)&Ps[(w * 16 + row16) * PS_STRIDE + kk2 * 32 + quad * 8];
#pragma unroll
      for (int dt = 0; dt < 8; ++dt) {
        bf16x8 vfr = *(const bf16x8*)&Vt[(dt * 16 + row16) * VT_STRIDE + kk2 * 32 + quad * 8];
        o[dt] = __builtin_amdgcn_mfma_f32_16x16x32_bf16(pa, vfr, o[dt], 0, 0, 0);
      }
    }
  }

#pragma unroll
  for (int r = 0; r < 4; ++r) {
    float inv = 1.0f / lrow[r];
    int row = q0 + w * 16 + quad * 4 + r;
    size_t obase = ((size_t)(b * 2048 + row)) * 3072 + (size_t)h * 128;
#pragma unroll
    for (int dt = 0; dt < 8; ++dt)
      attnb[obase + dt * 16 + row16] = f2bf(o[dt][r] * inv);
  }
}

// ---------------- workspace layout (bytes) ----------------
#define SZ_XB     ((size_t)4096 * 3072 * 2)
#define SZ_WQKVB  ((size_t)5120 * 3072 * 2)
#define SZ_AQKVB  ((size_t)256 * 3072 * 2)
#define SZ_BQKVB  ((size_t)5120 * 256 * 2)
#define SZ_WOB    ((size_t)3072 * 3072 * 2)
#define SZ_AOB    ((size_t)256 * 3072 * 2)
#define SZ_BOB    ((size_t)3072 * 256 * 2)
#define SZ_QKV    ((size_t)4096 * 5120 * 4)
#define SZ_TA     ((size_t)4096 * 256 * 4)
#define SZ_TAB    ((size_t)4096 * 256 * 2)

#define OFF_XB    ((size_t)0)
#define OFF_WQKVB (OFF_XB + SZ_XB)
#define OFF_AQKVB (OFF_WQKVB + SZ_WQKVB)
#define OFF_BQKVB (OFF_AQKVB + SZ_AQKVB)
#define OFF_WOB   (OFF_BQKVB + SZ_BQKVB)
#define OFF_AOB   (OFF_WOB + SZ_WOB)
#define OFF_BOB   (OFF_AOB + SZ_AOB)
#define OFF_QKV   (OFF_BOB + SZ_BOB)
#define OFF_TA    (OFF_QKV + SZ_QKV)
#define OFF_TAB   (OFF_TA + SZ_TA)
#define OFF_QB    OFF_XB
#define OFF_KB    OFF_WQKVB
#define OFF_VTG   (OFF_WQKVB + (size_t)8388608)
#define OFF_ATTNB OFF_QKV
#define OFF_TO    (OFF_QKV + (size_t)25165824)
#define OFF_TOB   (OFF_TO + (size_t)4194304)

static inline void launch_cast(const float* in, u16* out, int n, hipStream_t s) {
  int n8 = n >> 3;
  int blocks = (n8 + 255) / 256;
  if (blocks > 2048) blocks = 2048;
  k_cast_bf16v<<<blocks, 256, 0, s>>>(in, out, n8);
}

extern "C" void kernel_launch(void* const* d_in, const int* in_sizes, int n_in,
                              void* d_out, int out_size, void* d_ws, size_t ws_size,
                              hipStream_t stream) {
  const float* x    = (const float*)d_in[0];
  const float* Wqkv = (const float*)d_in[1];
  const float* Aqkv = (const float*)d_in[2];
  const float* Bqkv = (const float*)d_in[3];
  const float* Wo   = (const float*)d_in[4];
  const float* Ao   = (const float*)d_in[5];
  const float* Bo   = (const float*)d_in[6];
  const int*   pos  = (const int*)d_in[7];
  float* out = (float*)d_out;
  char* ws = (char*)d_ws;

  u16* xb    = (u16*)(ws + OFF_XB);
  u16* wqkvb = (u16*)(ws + OFF_WQKVB);
  u16* aqkvb = (u16*)(ws + OFF_AQKVB);
  u16* bqkvb = (u16*)(ws + OFF_BQKVB);
  u16* wob   = (u16*)(ws + OFF_WOB);
  u16* aob   = (u16*)(ws + OFF_AOB);
  u16* bob   = (u16*)(ws + OFF_BOB);
  float* qkv = (float*)(ws + OFF_QKV);
  float* tA  = (float*)(ws + OFF_TA);
  u16* tab   = (u16*)(ws + OFF_TAB);
  u16* qb    = (u16*)(ws + OFF_QB);
  u16* kb    = (u16*)(ws + OFF_KB);
  u16* vtg   = (u16*)(ws + OFF_VTG);
  u16* attnb = (u16*)(ws + OFF_ATTNB);
  float* tO  = (float*)(ws + OFF_TO);
  u16* tob   = (u16*)(ws + OFF_TOB);

  // 1) casts
  launch_cast(x,    xb,    4096 * 3072, stream);
  launch_cast(Wqkv, wqkvb, 5120 * 3072, stream);
  launch_cast(Aqkv, aqkvb, 256 * 3072,  stream);
  launch_cast(Bqkv, bqkvb, 5120 * 256,  stream);
  launch_cast(Wo,   wob,   3072 * 3072, stream);
  launch_cast(Ao,   aob,   256 * 3072,  stream);
  launch_cast(Bo,   bob,   3072 * 256,  stream);

  // 2) qkv = x @ Wqkv^T + 2 * (x @ Aqkv^T) @ Bqkv^T
  k_gemm256<<<dim3((5120 / 256) * (4096 / 256)), 512, 0, stream>>>(xb, wqkvb, qkv, 4096, 5120, 3072);
  k_gemm_bt<<<dim3(256 / 64, 4096 / 64), 256, 0, stream>>>(xb, aqkvb, tA, 4096, 256, 3072, 1.f, 0);
  launch_cast(tA, tab, 4096 * 256, stream);
  k_gemm_bt<<<dim3(5120 / 64, 4096 / 64), 256, 0, stream>>>(tab, bqkvb, qkv, 4096, 5120, 256, 2.0f, 1);

  // 3) rope+split q,k ; transpose-cast v
  k_rope_split<<<dim3(4096, 32), 128, 0, stream>>>(qkv, pos, qb, kb);
  k_vtrans<<<dim3(256, 16), 128, 0, stream>>>(qkv, vtg);

  // 4) MFMA flash attention
  k_attn_mfma<<<dim3(32, 48), 256, 0, stream>>>(qb, kb, vtg, attnb);

  // 5) out = attn @ Wo^T + 2 * (attn @ Ao^T) @ Bo^T
  k_gemm256<<<dim3((3072 / 256) * (4096 / 256)), 512, 0, stream>>>(attnb, wob, out, 4096, 3072, 3072);
  k_gemm_bt<<<dim3(256 / 64, 4096 / 64), 256, 0, stream>>>(attnb, aob, tO, 4096, 256, 3072, 1.f, 0);
  launch_cast(tO, tob, 4096 * 256, stream);
  k_gemm_bt<<<dim3(3072 / 64, 4096 / 64), 256, 0, stream>>>(tob, bob, out, 4096, 3072, 256, 2.0f, 1);
}

// Round 3
// 823.800 us; speedup vs baseline: 1.3147x; 1.1290x over previous
//
#include <hip/hip_runtime.h>

typedef unsigned short u16;
typedef unsigned int   u32;

typedef __bf16 bf16_t;
typedef bf16_t bf16x8 __attribute__((ext_vector_type(8)));
typedef float  f32x4  __attribute__((ext_vector_type(4)));
typedef u16    u16x8  __attribute__((ext_vector_type(8)));

__device__ __forceinline__ float bf2f(u16 u) { return __uint_as_float(((u32)u) << 16); }
__device__ __forceinline__ u16 f2bf(float f) {
  u32 u = __float_as_uint(f);
  u32 r = u + 0x7fffu + ((u >> 16) & 1u);
  return (u16)(r >> 16);
}
__device__ __forceinline__ float fast_exp2(float x) { return __builtin_amdgcn_exp2f(x); }

__device__ __forceinline__ void gload_lds16(const u16* g, u16* l) {
  __builtin_amdgcn_global_load_lds(
      (const __attribute__((address_space(1))) void*)g,
      (__attribute__((address_space(3))) void*)l,
      16, 0, 0);
}

// ---------------- cast f32 -> bf16 (vectorized: 8 elems/thread) ----------------
__global__ void k_cast_bf16v(const float* __restrict__ in, u16* __restrict__ out, int n8) {
  int i = blockIdx.x * blockDim.x + threadIdx.x;
  int stride = gridDim.x * blockDim.x;
  for (; i < n8; i += stride) {
    const f32x4* p = (const f32x4*)(in + (size_t)i * 8);
    f32x4 a = p[0], b = p[1];
    u16x8 o;
    o[0] = f2bf(a[0]); o[1] = f2bf(a[1]); o[2] = f2bf(a[2]); o[3] = f2bf(a[3]);
    o[4] = f2bf(b[0]); o[5] = f2bf(b[1]); o[6] = f2bf(b[2]); o[7] = f2bf(b[3]);
    *(u16x8*)(out + (size_t)i * 8) = o;
  }
}

// ---------------- small GEMM (64x64 tile) for N=256 / K=256 cases ----------------
#define GBM 64
#define GBN 64
#define GBK 64

__global__ __launch_bounds__(256) void k_gemm_bt(
    const u16* __restrict__ A, const u16* __restrict__ B, float* __restrict__ C,
    int M, int N, int K, float alpha, int beta) {
  __shared__ u16 As[GBM][GBK + 8];
  __shared__ u16 Bs[GBN][GBK + 8];
  const int tid   = threadIdx.x;
  const int lane  = tid & 63;
  const int w     = tid >> 6;
  const int wm    = (w >> 1) * 32;
  const int wn    = (w & 1) * 32;
  const int row16 = lane & 15;
  const int quad  = lane >> 4;
  const int m0 = blockIdx.y * GBM;
  const int n0 = blockIdx.x * GBN;
  const int ldr = tid >> 2;
  const int ldc = (tid & 3) * 16;

  f32x4 acc[2][2] = {};

  for (int k0 = 0; k0 < K; k0 += GBK) {
    const u16* ga = A + (size_t)(m0 + ldr) * K + (k0 + ldc);
    const u16* gb = B + (size_t)(n0 + ldr) * K + (k0 + ldc);
    u16x8 a0 = *(const u16x8*)ga;
    u16x8 a1 = *(const u16x8*)(ga + 8);
    u16x8 b0 = *(const u16x8*)gb;
    u16x8 b1 = *(const u16x8*)(gb + 8);
    __syncthreads();
    *(u16x8*)&As[ldr][ldc]     = a0;
    *(u16x8*)&As[ldr][ldc + 8] = a1;
    *(u16x8*)&Bs[ldr][ldc]     = b0;
    *(u16x8*)&Bs[ldr][ldc + 8] = b1;
    __syncthreads();
#pragma unroll
    for (int kk = 0; kk < GBK; kk += 32) {
      bf16x8 af0 = *(const bf16x8*)&As[wm + row16][kk + quad * 8];
      bf16x8 af1 = *(const bf16x8*)&As[wm + 16 + row16][kk + quad * 8];
      bf16x8 bg0 = *(const bf16x8*)&Bs[wn + row16][kk + quad * 8];
      bf16x8 bg1 = *(const bf16x8*)&Bs[wn + 16 + row16][kk + quad * 8];
      acc[0][0] = __builtin_amdgcn_mfma_f32_16x16x32_bf16(af0, bg0, acc[0][0], 0, 0, 0);
      acc[0][1] = __builtin_amdgcn_mfma_f32_16x16x32_bf16(af0, bg1, acc[0][1], 0, 0, 0);
      acc[1][0] = __builtin_amdgcn_mfma_f32_16x16x32_bf16(af1, bg0, acc[1][0], 0, 0, 0);
      acc[1][1] = __builtin_amdgcn_mfma_f32_16x16x32_bf16(af1, bg1, acc[1][1], 0, 0, 0);
    }
  }
#pragma unroll
  for (int tm = 0; tm < 2; ++tm)
#pragma unroll
    for (int tn = 0; tn < 2; ++tn) {
      int gm = m0 + wm + tm * 16 + quad * 4;
      int gn = n0 + wn + tn * 16 + row16;
#pragma unroll
      for (int r = 0; r < 4; ++r) {
        size_t idx = (size_t)(gm + r) * N + gn;
        float v = alpha * acc[tm][tn][r];
        if (beta) v += C[idx];
        C[idx] = v;
      }
    }
}

// ================= 256x256 8-phase GEMM (m201 template, plain HIP) =================
__device__ __forceinline__ void stage_half(
    int H, int nt4,
    const u16* __restrict__ A, const u16* __restrict__ B, int K,
    int m0, int n0, u16* AsB, u16* BsB,
    int w, int rowin, int colsw) {
  if (H >= nt4) return;
  const int t = H >> 2, slot = H & 3;
  const int half = slot & 1;
  const u16* G = (slot < 2) ? A : B;
  const int r0 = (slot < 2) ? m0 : n0;
  u16* lds = ((slot < 2) ? AsB : BsB) + (t & 1) * 16384 + half * 8192;
  const int k0 = t * 64;
#pragma unroll
  for (int i = 0; i < 2; ++i) {
    const int chunk = w * 2 + i;
    const int row = half * 128 + chunk * 8 + rowin;
    gload_lds16(G + (size_t)(r0 + row) * K + k0 + colsw, lds + chunk * 512);
  }
}

__device__ __forceinline__ bf16x8 frag_ld(const u16* base, int row, int c16) {
  return *(const bf16x8*)(base + row * 64 + ((c16 ^ (row & 7)) << 3));
}

#define SBAR0() __builtin_amdgcn_sched_barrier(0)
#define HWBAR() __builtin_amdgcn_s_barrier()

template <int RB>
__device__ __forceinline__ void gemm256_group(
    int k, int nt,
    const u16* __restrict__ A, const u16* __restrict__ B, int K,
    int m0, int n0, u16* AsB, u16* BsB,
    int wr, int wc, int row16, int quad, int w, int rowin, int colsw,
    f32x4 (&acc)[8][4]) {
  const u16* Ab = AsB + RB * 16384;
  const u16* Bb = BsB + RB * 16384;
  const int nt4 = nt * 4;
  bf16x8 a0[4][2], a1[4][2], b0[2][2], b1[2][2];

#pragma unroll
  for (int mf = 0; mf < 4; ++mf)
#pragma unroll
    for (int kk = 0; kk < 2; ++kk)
      a0[mf][kk] = frag_ld(Ab, wr * 128 + mf * 16 + row16, kk * 4 + quad);
#pragma unroll
  for (int nf = 0; nf < 2; ++nf)
#pragma unroll
    for (int kk = 0; kk < 2; ++kk)
      b0[nf][kk] = frag_ld(Bb, wc * 64 + nf * 16 + row16, kk * 4 + quad);
  stage_half(4 * k + 5, nt4, A, B, K, m0, n0, AsB, BsB, w, rowin, colsw);
  SBAR0(); HWBAR(); SBAR0();
  __builtin_amdgcn_s_setprio(1);
#pragma unroll
  for (int mf = 0; mf < 4; ++mf)
#pragma unroll
    for (int nf = 0; nf < 2; ++nf)
#pragma unroll
      for (int kk = 0; kk < 2; ++kk)
        acc[mf][nf] = __builtin_amdgcn_mfma_f32_16x16x32_bf16(a0[mf][kk], b0[nf][kk], acc[mf][nf], 0, 0, 0);
  __builtin_amdgcn_s_setprio(0);
  SBAR0(); HWBAR(); SBAR0();

#pragma unroll
  for (int nf = 0; nf < 2; ++nf)
#pragma unroll
    for (int kk = 0; kk < 2; ++kk)
      b1[nf][kk] = frag_ld(Bb, wc * 64 + 32 + nf * 16 + row16, kk * 4 + quad);
  stage_half(4 * k + 6, nt4, A, B, K, m0, n0, AsB, BsB, w, rowin, colsw);
  SBAR0(); HWBAR(); SBAR0();
  __builtin_amdgcn_s_setprio(1);
#pragma unroll
  for (int mf = 0; mf < 4; ++mf)
#pragma unroll
    for (int nf = 0; nf < 2; ++nf)
#pragma unroll
      for (int kk = 0; kk < 2; ++kk)
        acc[mf][2 + nf] = __builtin_amdgcn_mfma_f32_16x16x32_bf16(a0[mf][kk], b1[nf][kk], acc[mf][2 + nf], 0, 0, 0);
  __builtin_amdgcn_s_setprio(0);
  SBAR0(); HWBAR(); SBAR0();

#pragma unroll
  for (int mf = 0; mf < 4; ++mf)
#pragma unroll
    for (int kk = 0; kk < 2; ++kk)
      a1[mf][kk] = frag_ld(Ab, wr * 128 + 64 + mf * 16 + row16, kk * 4 + quad);
  stage_half(4 * k + 7, nt4, A, B, K, m0, n0, AsB, BsB, w, rowin, colsw);
  SBAR0(); HWBAR(); SBAR0();
  __builtin_amdgcn_s_setprio(1);
#pragma unroll
  for (int mf = 0; mf < 4; ++mf)
#pragma unroll
    for (int nf = 0; nf < 2; ++nf)
#pragma unroll
      for (int kk = 0; kk < 2; ++kk)
        acc[4 + mf][nf] = __builtin_amdgcn_mfma_f32_16x16x32_bf16(a1[mf][kk], b0[nf][kk], acc[4 + mf][nf], 0, 0, 0);
  __builtin_amdgcn_s_setprio(0);
  SBAR0(); HWBAR(); SBAR0();

  stage_half(4 * k + 8, nt4, A, B, K, m0, n0, AsB, BsB, w, rowin, colsw);
  SBAR0();
  if (k < nt - 2) { asm volatile("s_waitcnt vmcnt(2)" ::: "memory"); }
  else            { asm volatile("s_waitcnt vmcnt(0)" ::: "memory"); }
  HWBAR(); SBAR0();
  __builtin_amdgcn_s_setprio(1);
#pragma unroll
  for (int mf = 0; mf < 4; ++mf)
#pragma unroll
    for (int nf = 0; nf < 2; ++nf)
#pragma unroll
      for (int kk = 0; kk < 2; ++kk)
        acc[4 + mf][2 + nf] = __builtin_amdgcn_mfma_f32_16x16x32_bf16(a1[mf][kk], b1[nf][kk], acc[4 + mf][2 + nf], 0, 0, 0);
  __builtin_amdgcn_s_setprio(0);
  SBAR0(); HWBAR(); SBAR0();
}

__global__ __launch_bounds__(512, 2) void k_gemm256(
    const u16* __restrict__ A, const u16* __restrict__ B, float* __restrict__ C,
    int M, int N, int K) {
  __shared__ u16 As[2 * 16384];
  __shared__ u16 Bs[2 * 16384];

  const int tid   = threadIdx.x;
  const int lane  = tid & 63;
  const int w     = tid >> 6;
  const int wr    = w >> 2;
  const int wc    = w & 3;
  const int row16 = lane & 15;
  const int quad  = lane >> 4;
  const int rowin = lane >> 3;
  const int colsw = ((lane & 7) ^ (lane >> 3)) << 3;

  const int nwg = (int)gridDim.x;
  const int bid = (int)blockIdx.x;
  const int xcd = bid & 7, rest = bid >> 3;
  const int qq = nwg >> 3, rr = nwg & 7;
  const int wg = (xcd < rr ? xcd * (qq + 1) : rr * (qq + 1) + (xcd - rr) * qq) + rest;
  const int nbx = N >> 8;
  const int m0 = (wg / nbx) << 8;
  const int n0 = (wg % nbx) << 8;

  const int nt = K >> 6;
  f32x4 acc[8][4] = {};

#pragma unroll
  for (int H = 0; H < 5; ++H)
    stage_half(H, nt * 4, A, B, K, m0, n0, As, Bs, w, rowin, colsw);
  asm volatile("s_waitcnt vmcnt(2)" ::: "memory");
  HWBAR(); SBAR0();

  int k = 0;
  for (; k + 1 < nt; k += 2) {
    gemm256_group<0>(k,     nt, A, B, K, m0, n0, As, Bs, wr, wc, row16, quad, w, rowin, colsw, acc);
    gemm256_group<1>(k + 1, nt, A, B, K, m0, n0, As, Bs, wr, wc, row16, quad, w, rowin, colsw, acc);
  }
  if (k < nt)
    gemm256_group<0>(k, nt, A, B, K, m0, n0, As, Bs, wr, wc, row16, quad, w, rowin, colsw, acc);

#pragma unroll
  for (int mi = 0; mi < 8; ++mi) {
    const int gm = m0 + wr * 128 + mi * 16 + quad * 4;
#pragma unroll
    for (int nj = 0; nj < 4; ++nj) {
      const int gn = n0 + wc * 64 + nj * 16 + row16;
#pragma unroll
      for (int r = 0; r < 4; ++r)
        C[(size_t)(gm + r) * N + gn] = acc[mi][nj][r];
    }
  }
}

// ---------------- RoPE cos/sin table: tab[r][0..47]=cos, tab[r][48..95]=sin ----------------
__global__ void k_rope_tab(const int* __restrict__ pos_ids, float* __restrict__ tab) {
  const int t = threadIdx.x;          // 0..191
  const int r = blockIdx.x * 4 + t / 48;
  const int j = t % 48;
  const float pos = (float)pos_ids[r];
  float invf = powf(10000.0f, -(float)j * (1.0f / 48.0f));
  float e = pos * invf;
  tab[(size_t)r * 96 + j]      = cosf(e);
  tab[(size_t)r * 96 + 48 + j] = sinf(e);
}

// ---------------- RoPE + split q,k (v handled by k_vtrans) ----------------
__global__ void k_rope_split(const float* __restrict__ qkv, const float* __restrict__ tab,
                             u16* __restrict__ qb, u16* __restrict__ kb) {
  const int r  = blockIdx.x;
  const int hh = blockIdx.y;
  const int d  = threadIdx.x;
  const float* src;
  if (hh < 24) src = qkv + (size_t)r * 5120 + hh * 128;
  else         src = qkv + (size_t)r * 5120 + 3072 + (hh - 24) * 128;
  float x = src[d];
  float outv;
  if (d >= 96) {
    outv = x;
  } else {
    int j = (d < 48) ? d : d - 48;
    float c  = tab[(size_t)r * 96 + j];
    float sn = tab[(size_t)r * 96 + 48 + j];
    if (d < 48) outv = x * c - src[d + 48] * sn;
    else        outv = x * c + src[d - 48] * sn;
  }
  u16 o = f2bf(outv);
  if (hh < 24) qb[((size_t)r * 24 + hh) * 128 + d] = o;
  else         kb[((size_t)r * 8 + (hh - 24)) * 128 + d] = o;
}

// ---------------- V transpose: qkv f32 -> vtg bf16 [b][kvh][d][key] ----------------
__global__ void k_vtrans(const float* __restrict__ qkv, u16* __restrict__ vtg) {
  const int d  = threadIdx.x;
  const int kg = blockIdx.x;
  const int bk = blockIdx.y;
  const int b = bk >> 3, kvh = bk & 7;
  const float* src = qkv + (size_t)(b * 2048 + kg * 8) * 5120 + 4096 + kvh * 128 + d;
  u16x8 pack;
#pragma unroll
  for (int t = 0; t < 8; ++t) pack[t] = f2bf(src[(size_t)t * 5120]);
  *(u16x8*)(vtg + ((size_t)bk * 128 + d) * 2048 + kg * 8) = pack;
}

// ---------------- MFMA flash attention (causal, GQA 24q/8kv, D=128) ----------------
// Swapped QK^T: S^T = mfma(K,Q) -> lane holds S[key=kb0+nt*16+quad*4+r][q=q0+w*16+row16]
// -> softmax row-reduce is in-lane (16 vals) + 2 cross-quad shfl_xor.
// T14 async-stage: next tile's K/V global loads issued before compute, LDS-written next iter.
#define KS_STRIDE 136
#define VT_STRIDE 72
#define PS_STRIDE 72

__global__ __launch_bounds__(256) void k_attn_mfma(
    const u16* __restrict__ qb, const u16* __restrict__ kb, const u16* __restrict__ vtg,
    u16* __restrict__ attnb) {
  __shared__ u16 Ks[64 * KS_STRIDE];
  __shared__ u16 Vt[128 * VT_STRIDE];
  __shared__ u16 Ps[4 * 16 * PS_STRIDE];

  const int tid   = threadIdx.x;
  const int lane  = tid & 63;
  const int w     = tid >> 6;
  const int row16 = lane & 15;
  const int quad  = lane >> 4;
  const int qt  = (int)gridDim.x - 1 - (int)blockIdx.x;
  const int bh  = blockIdx.y;
  const int b   = bh / 24;
  const int h   = bh % 24;
  const int kvh = h / 3;
  const int q0  = qt * 64;

  const u16* qbase = qb + (((size_t)(b * 2048 + q0 + w * 16 + row16)) * 24 + h) * 128;
  bf16x8 qfrag[4];
#pragma unroll
  for (int kk = 0; kk < 4; ++kk) qfrag[kk] = *(const bf16x8*)(qbase + kk * 32 + quad * 8);

  const u16* kbbase = kb + ((size_t)(b * 2048) * 8 + kvh) * 128;
  const u16* vtbase = vtg + (size_t)(b * 8 + kvh) * 128 * 2048;

  f32x4 o[8] = {};
  float m_st = -INFINITY;
  float l_st = 0.f;
  const float C1 = 0.08838834764831845f * 1.4426950408889634f;  // SCALE * log2(e)
  const int qrow = q0 + w * 16 + row16;   // this lane's query row (global)

  // T14: register-staged tile data for the NEXT tile to be LDS-written
  u16x8 kr[4], vr[4];
  // prologue: load tile 0
#pragma unroll
  for (int i = 0; i < 4; ++i) {
    int c = tid + i * 256;
    int kk = c >> 4, d8 = (c & 15) * 8;
    kr[i] = *(const u16x8*)(kbbase + (size_t)kk * 1024 + d8);
  }
#pragma unroll
  for (int i = 0; i < 4; ++i) {
    int c = tid + i * 256;
    int d = c >> 3, k8 = (c & 7) * 8;
    vr[i] = *(const u16x8*)(vtbase + (size_t)d * 2048 + k8);
  }

  for (int t = 0; t <= qt; ++t) {
    const int kb0 = t * 64;
    __syncthreads();  // all waves done READING the previous tile's LDS
    // write staged regs -> LDS
#pragma unroll
    for (int i = 0; i < 4; ++i) {
      int c = tid + i * 256;
      int kk = c >> 4, d8 = (c & 15) * 8;
      *(u16x8*)&Ks[kk * KS_STRIDE + d8] = kr[i];
    }
#pragma unroll
    for (int i = 0; i < 4; ++i) {
      int c = tid + i * 256;
      int d = c >> 3, k8 = (c & 7) * 8;
      *(u16x8*)&Vt[d * VT_STRIDE + k8] = vr[i];
    }
    __syncthreads();  // tile resident
    // issue next-tile loads now; latency hides under QK+softmax+PV
    if (t < qt) {
      const int nb0 = kb0 + 64;
#pragma unroll
      for (int i = 0; i < 4; ++i) {
        int c = tid + i * 256;
        int kk = c >> 4, d8 = (c & 15) * 8;
        kr[i] = *(const u16x8*)(kbbase + (size_t)(nb0 + kk) * 1024 + d8);
      }
#pragma unroll
      for (int i = 0; i < 4; ++i) {
        int c = tid + i * 256;
        int d = c >> 3, k8 = (c & 7) * 8;
        vr[i] = *(const u16x8*)(vtbase + (size_t)d * 2048 + nb0 + k8);
      }
    }

    // S^T = K Q^T  (swapped operands; fragment reads identical to before)
    f32x4 s[4] = {};
#pragma unroll
    for (int kk = 0; kk < 4; ++kk) {
#pragma unroll
      for (int nt = 0; nt < 4; ++nt) {
        bf16x8 kfr = *(const bf16x8*)&Ks[(nt * 16 + row16) * KS_STRIDE + kk * 32 + quad * 8];
        s[nt] = __builtin_amdgcn_mfma_f32_16x16x32_bf16(kfr, qfrag[kk], s[nt], 0, 0, 0);
      }
    }

    // causal mask on diagonal tile: key = kb0 + nt*16 + quad*4 + r, query = qrow
    if (t == qt) {
#pragma unroll
      for (int nt = 0; nt < 4; ++nt) {
        int kbase = kb0 + nt * 16 + quad * 4;
#pragma unroll
        for (int r = 0; r < 4; ++r)
          if (kbase + r > qrow) s[nt][r] = -INFINITY;
      }
    }

    // online softmax: in-lane over 16 keys + 2-step cross-quad reduce
    float mx = s[0][0];
#pragma unroll
    for (int nt = 0; nt < 4; ++nt)
#pragma unroll
      for (int r = 0; r < 4; ++r) mx = fmaxf(mx, s[nt][r]);
    mx = fmaxf(mx, __shfl_xor(mx, 16));
    mx = fmaxf(mx, __shfl_xor(mx, 32));
    float mnew = fmaxf(m_st, mx);
    float alpha = fast_exp2((m_st - mnew) * C1);  // first tile: exp2(-inf)=0
    m_st = mnew;
    float rs = 0.f;
#pragma unroll
    for (int nt = 0; nt < 4; ++nt)
#pragma unroll
      for (int r = 0; r < 4; ++r) {
        float p = fast_exp2((s[nt][r] - mnew) * C1);
        s[nt][r] = p;
        rs += p;
      }
    rs += __shfl_xor(rs, 16);
    rs += __shfl_xor(rs, 32);
    l_st = l_st * alpha + rs;
    // o fragments belong to query quad*4+r; fetch that query's alpha from lane (quad*4+r)
#pragma unroll
    for (int r = 0; r < 4; ++r) {
      float ar = __shfl(alpha, quad * 4 + r, 64);
#pragma unroll
      for (int dt = 0; dt < 8; ++dt) o[dt][r] *= ar;
    }

    // P^T (lane: one q-row = row16, 16 keys) -> Ps[q][key]
#pragma unroll
    for (int nt = 0; nt < 4; ++nt)
#pragma unroll
      for (int r = 0; r < 4; ++r)
        Ps[(w * 16 + row16) * PS_STRIDE + nt * 16 + quad * 4 + r] = f2bf(s[nt][r]);
    // wave-synchronous LDS write->read within the same wave

    // O += P V  (unchanged)
#pragma unroll
    for (int kk2 = 0; kk2 < 2; ++kk2) {
      bf16x8 pa = *(const bf16x8*)&Ps[(w * 16 + row16) * PS_STRIDE + kk2 * 32 + quad * 8];
#pragma unroll
      for (int dt = 0; dt < 8; ++dt) {
        bf16x8 vfr = *(const bf16x8*)&Vt[(dt * 16 + row16) * VT_STRIDE + kk2 * 32 + quad * 8];
        o[dt] = __builtin_amdgcn_mfma_f32_16x16x32_bf16(pa, vfr, o[dt], 0, 0, 0);
      }
    }
  }

  // epilogue: normalize (l for query quad*4+r lives in lane quad*4+r) and store bf16
#pragma unroll
  for (int r = 0; r < 4; ++r) {
    float lq = __shfl(l_st, quad * 4 + r, 64);
    float inv = 1.0f / lq;
    int row = q0 + w * 16 + quad * 4 + r;
    size_t obase = ((size_t)(b * 2048 + row)) * 3072 + (size_t)h * 128;
#pragma unroll
    for (int dt = 0; dt < 8; ++dt)
      attnb[obase + dt * 16 + row16] = f2bf(o[dt][r] * inv);
  }
}

// ---------------- workspace layout (bytes) ----------------
#define SZ_XB     ((size_t)4096 * 3072 * 2)
#define SZ_WQKVB  ((size_t)5120 * 3072 * 2)
#define SZ_AQKVB  ((size_t)256 * 3072 * 2)
#define SZ_BQKVB  ((size_t)5120 * 256 * 2)
#define SZ_WOB    ((size_t)3072 * 3072 * 2)
#define SZ_AOB    ((size_t)256 * 3072 * 2)
#define SZ_BOB    ((size_t)3072 * 256 * 2)
#define SZ_QKV    ((size_t)4096 * 5120 * 4)
#define SZ_TA     ((size_t)4096 * 256 * 4)
#define SZ_TAB    ((size_t)4096 * 256 * 2)

#define OFF_XB    ((size_t)0)
#define OFF_WQKVB (OFF_XB + SZ_XB)
#define OFF_AQKVB (OFF_WQKVB + SZ_WQKVB)
#define OFF_BQKVB (OFF_AQKVB + SZ_AQKVB)
#define OFF_WOB   (OFF_BQKVB + SZ_BQKVB)
#define OFF_AOB   (OFF_WOB + SZ_WOB)
#define OFF_BOB   (OFF_AOB + SZ_AOB)
#define OFF_QKV   (OFF_BOB + SZ_BOB)
#define OFF_TA    (OFF_QKV + SZ_QKV)
#define OFF_TAB   (OFF_TA + SZ_TA)
#define OFF_QB    OFF_XB
#define OFF_KB    OFF_WQKVB
#define OFF_VTG   (OFF_WQKVB + (size_t)8388608)
#define OFF_RTAB  (OFF_WQKVB + (size_t)16777216)  // rope table 1.5 MB in dead wqkvb tail
#define OFF_ATTNB OFF_QKV
#define OFF_TO    (OFF_QKV + (size_t)25165824)
#define OFF_TOB   (OFF_TO + (size_t)4194304)

static inline void launch_cast(const float* in, u16* out, int n, hipStream_t s) {
  int n8 = n >> 3;
  int blocks = (n8 + 255) / 256;
  if (blocks > 2048) blocks = 2048;
  k_cast_bf16v<<<blocks, 256, 0, s>>>(in, out, n8);
}

extern "C" void kernel_launch(void* const* d_in, const int* in_sizes, int n_in,
                              void* d_out, int out_size, void* d_ws, size_t ws_size,
                              hipStream_t stream) {
  const float* x    = (const float*)d_in[0];
  const float* Wqkv = (const float*)d_in[1];
  const float* Aqkv = (const float*)d_in[2];
  const float* Bqkv = (const float*)d_in[3];
  const float* Wo   = (const float*)d_in[4];
  const float* Ao   = (const float*)d_in[5];
  const float* Bo   = (const float*)d_in[6];
  const int*   pos  = (const int*)d_in[7];
  float* out = (float*)d_out;
  char* ws = (char*)d_ws;

  u16* xb    = (u16*)(ws + OFF_XB);
  u16* wqkvb = (u16*)(ws + OFF_WQKVB);
  u16* aqkvb = (u16*)(ws + OFF_AQKVB);
  u16* bqkvb = (u16*)(ws + OFF_BQKVB);
  u16* wob   = (u16*)(ws + OFF_WOB);
  u16* aob   = (u16*)(ws + OFF_AOB);
  u16* bob   = (u16*)(ws + OFF_BOB);
  float* qkv = (float*)(ws + OFF_QKV);
  float* tA  = (float*)(ws + OFF_TA);
  u16* tab   = (u16*)(ws + OFF_TAB);
  u16* qb    = (u16*)(ws + OFF_QB);
  u16* kb    = (u16*)(ws + OFF_KB);
  u16* vtg   = (u16*)(ws + OFF_VTG);
  float* rtab = (float*)(ws + OFF_RTAB);
  u16* attnb = (u16*)(ws + OFF_ATTNB);
  float* tO  = (float*)(ws + OFF_TO);
  u16* tob   = (u16*)(ws + OFF_TOB);

  // 1) casts
  launch_cast(x,    xb,    4096 * 3072, stream);
  launch_cast(Wqkv, wqkvb, 5120 * 3072, stream);
  launch_cast(Aqkv, aqkvb, 256 * 3072,  stream);
  launch_cast(Bqkv, bqkvb, 5120 * 256,  stream);
  launch_cast(Wo,   wob,   3072 * 3072, stream);
  launch_cast(Ao,   aob,   256 * 3072,  stream);
  launch_cast(Bo,   bob,   3072 * 256,  stream);

  // 2) qkv = x @ Wqkv^T + 2 * (x @ Aqkv^T) @ Bqkv^T
  k_gemm256<<<dim3((5120 / 256) * (4096 / 256)), 512, 0, stream>>>(xb, wqkvb, qkv, 4096, 5120, 3072);
  k_gemm_bt<<<dim3(256 / 64, 4096 / 64), 256, 0, stream>>>(xb, aqkvb, tA, 4096, 256, 3072, 1.f, 0);
  launch_cast(tA, tab, 4096 * 256, stream);
  k_gemm_bt<<<dim3(5120 / 64, 4096 / 64), 256, 0, stream>>>(tab, bqkvb, qkv, 4096, 5120, 256, 2.0f, 1);

  // 3) rope table (wqkvb dead now) ; rope+split q,k ; transpose-cast v
  k_rope_tab<<<dim3(1024), 192, 0, stream>>>(pos, rtab);
  k_rope_split<<<dim3(4096, 32), 128, 0, stream>>>(qkv, rtab, qb, kb);
  k_vtrans<<<dim3(256, 16), 128, 0, stream>>>(qkv, vtg);

  // 4) MFMA flash attention
  k_attn_mfma<<<dim3(32, 48), 256, 0, stream>>>(qb, kb, vtg, attnb);

  // 5) out = attn @ Wo^T + 2 * (attn @ Ao^T) @ Bo^T
  k_gemm256<<<dim3((3072 / 256) * (4096 / 256)), 512, 0, stream>>>(attnb, wob, out, 4096, 3072, 3072);
  k_gemm_bt<<<dim3(256 / 64, 4096 / 64), 256, 0, stream>>>(attnb, aob, tO, 4096, 256, 3072, 1.f, 0);
  launch_cast(tO, tob, 4096 * 256, stream);
  k_gemm_bt<<<dim3(3072 / 64, 4096 / 64), 256, 0, stream>>>(tob, bob, out, 4096, 3072, 256, 2.0f, 1);
}

// Round 4
// 736.285 us; speedup vs baseline: 1.4710x; 1.1189x over previous
//
#include <hip/hip_runtime.h>

typedef unsigned short u16;
typedef unsigned int   u32;

typedef __bf16 bf16_t;
typedef bf16_t bf16x8 __attribute__((ext_vector_type(8)));
typedef float  f32x4  __attribute__((ext_vector_type(4)));
typedef u16    u16x8  __attribute__((ext_vector_type(8)));

__device__ __forceinline__ float bf2f(u16 u) { return __uint_as_float(((u32)u) << 16); }
__device__ __forceinline__ u16 f2bf(float f) {
  u32 u = __float_as_uint(f);
  u32 r = u + 0x7fffu + ((u >> 16) & 1u);
  return (u16)(r >> 16);
}
__device__ __forceinline__ float fast_exp2(float x) { return __builtin_amdgcn_exp2f(x); }

__device__ __forceinline__ void gload_lds16(const u16* g, u16* l) {
  __builtin_amdgcn_global_load_lds(
      (const __attribute__((address_space(1))) void*)g,
      (__attribute__((address_space(3))) void*)l,
      16, 0, 0);
}

#define SBAR0() __builtin_amdgcn_sched_barrier(0)
#define HWBAR() __builtin_amdgcn_s_barrier()

// ---------------- strided cast f32 -> bf16 (8 elems/thread, optional scale) ----------------
// in: [R][C8*8] f32 dense; out row stride L (u16), column offset off.
__global__ void k_cast_str(const float* __restrict__ in, u16* __restrict__ out,
                           int C8, int L, int off, float scale) {
  const int r  = blockIdx.y;
  const int c8 = blockIdx.x * 128 + threadIdx.x;
  if (c8 >= C8) return;
  const f32x4* p = (const f32x4*)(in + (size_t)r * (C8 * 8) + c8 * 8);
  f32x4 a = p[0], b = p[1];
  u16x8 o;
  o[0] = f2bf(a[0] * scale); o[1] = f2bf(a[1] * scale);
  o[2] = f2bf(a[2] * scale); o[3] = f2bf(a[3] * scale);
  o[4] = f2bf(b[0] * scale); o[5] = f2bf(b[1] * scale);
  o[6] = f2bf(b[2] * scale); o[7] = f2bf(b[3] * scale);
  *(u16x8*)(out + (size_t)r * L + off + c8 * 8) = o;
}

// ---------------- reduce 4 f32 slabs + scale + strided cast to bf16 ----------------
__global__ void k_red4_cast(const float* __restrict__ t4, u16* __restrict__ out,
                            int C8, int L, int off, float scale, size_t plane) {
  const int r  = blockIdx.y;
  const int c8 = blockIdx.x * 64 + threadIdx.x;
  if (c8 >= C8) return;
  size_t base = (size_t)r * (C8 * 8) + c8 * 8;
  float s[8];
#pragma unroll
  for (int j = 0; j < 8; ++j) s[j] = 0.f;
#pragma unroll
  for (int p = 0; p < 4; ++p) {
    const f32x4* q = (const f32x4*)(t4 + p * plane + base);
    f32x4 a = q[0], b = q[1];
    s[0] += a[0]; s[1] += a[1]; s[2] += a[2]; s[3] += a[3];
    s[4] += b[0]; s[5] += b[1]; s[6] += b[2]; s[7] += b[3];
  }
  u16x8 o;
#pragma unroll
  for (int j = 0; j < 8; ++j) o[j] = f2bf(s[j] * scale);
  *(u16x8*)(out + (size_t)r * L + off + c8 * 8) = o;
}

// ---------------- small GEMM (64x64 tile), split-K slabs ----------------
// Cz = A(M x kc@slab) @ B^T ; C has gridDim.z slabs of M*N f32.
__global__ __launch_bounds__(256) void k_gemm_bt_sk(
    const u16* __restrict__ A, const u16* __restrict__ B, float* __restrict__ C,
    int M, int N, int lda, int ldb, int kc) {
  __shared__ u16 As[64][64 + 8];
  __shared__ u16 Bs[64][64 + 8];
  const int tid   = threadIdx.x;
  const int lane  = tid & 63;
  const int w     = tid >> 6;
  const int wm    = (w >> 1) * 32;
  const int wn    = (w & 1) * 32;
  const int row16 = lane & 15;
  const int quad  = lane >> 4;
  const int m0 = blockIdx.y * 64;
  const int n0 = blockIdx.x * 64;
  const int ldr = tid >> 2;
  const int ldc = (tid & 3) * 16;
  const int z   = blockIdx.z;
  float* Cz = C + (size_t)z * M * N;
  const int kbeg = z * kc, kend = kbeg + kc;

  f32x4 acc[2][2] = {};

  for (int k0 = kbeg; k0 < kend; k0 += 64) {
    const u16* ga = A + (size_t)(m0 + ldr) * lda + (k0 + ldc);
    const u16* gb = B + (size_t)(n0 + ldr) * ldb + (k0 + ldc);
    u16x8 a0 = *(const u16x8*)ga;
    u16x8 a1 = *(const u16x8*)(ga + 8);
    u16x8 b0 = *(const u16x8*)gb;
    u16x8 b1 = *(const u16x8*)(gb + 8);
    __syncthreads();
    *(u16x8*)&As[ldr][ldc]     = a0;
    *(u16x8*)&As[ldr][ldc + 8] = a1;
    *(u16x8*)&Bs[ldr][ldc]     = b0;
    *(u16x8*)&Bs[ldr][ldc + 8] = b1;
    __syncthreads();
#pragma unroll
    for (int kk = 0; kk < 64; kk += 32) {
      bf16x8 af0 = *(const bf16x8*)&As[wm + row16][kk + quad * 8];
      bf16x8 af1 = *(const bf16x8*)&As[wm + 16 + row16][kk + quad * 8];
      bf16x8 bg0 = *(const bf16x8*)&Bs[wn + row16][kk + quad * 8];
      bf16x8 bg1 = *(const bf16x8*)&Bs[wn + 16 + row16][kk + quad * 8];
      acc[0][0] = __builtin_amdgcn_mfma_f32_16x16x32_bf16(af0, bg0, acc[0][0], 0, 0, 0);
      acc[0][1] = __builtin_amdgcn_mfma_f32_16x16x32_bf16(af0, bg1, acc[0][1], 0, 0, 0);
      acc[1][0] = __builtin_amdgcn_mfma_f32_16x16x32_bf16(af1, bg0, acc[1][0], 0, 0, 0);
      acc[1][1] = __builtin_amdgcn_mfma_f32_16x16x32_bf16(af1, bg1, acc[1][1], 0, 0, 0);
    }
  }
#pragma unroll
  for (int tm = 0; tm < 2; ++tm)
#pragma unroll
    for (int tn = 0; tn < 2; ++tn) {
      int gm = m0 + wm + tm * 16 + quad * 4;
      int gn = n0 + wn + tn * 16 + row16;
#pragma unroll
      for (int r = 0; r < 4; ++r)
        Cz[(size_t)(gm + r) * N + gn] = acc[tm][tn][r];
    }
}

// ================= 256x256 8-phase GEMM (m201 template, plain HIP) =================
__device__ __forceinline__ void stage_half(
    int H, int nt4,
    const u16* __restrict__ A, const u16* __restrict__ B, int K,
    int m0, int n0, u16* AsB, u16* BsB,
    int w, int rowin, int colsw) {
  if (H >= nt4) return;
  const int t = H >> 2, slot = H & 3;
  const int half = slot & 1;
  const u16* G = (slot < 2) ? A : B;
  const int r0 = (slot < 2) ? m0 : n0;
  u16* lds = ((slot < 2) ? AsB : BsB) + (t & 1) * 16384 + half * 8192;
  const int k0 = t * 64;
#pragma unroll
  for (int i = 0; i < 2; ++i) {
    const int chunk = w * 2 + i;
    const int row = half * 128 + chunk * 8 + rowin;
    gload_lds16(G + (size_t)(r0 + row) * K + k0 + colsw, lds + chunk * 512);
  }
}

__device__ __forceinline__ bf16x8 frag_ld(const u16* base, int row, int c16) {
  return *(const bf16x8*)(base + row * 64 + ((c16 ^ (row & 7)) << 3));
}

template <int RB>
__device__ __forceinline__ void gemm256_group(
    int k, int nt,
    const u16* __restrict__ A, const u16* __restrict__ B, int K,
    int m0, int n0, u16* AsB, u16* BsB,
    int wr, int wc, int row16, int quad, int w, int rowin, int colsw,
    f32x4 (&acc)[8][4]) {
  const u16* Ab = AsB + RB * 16384;
  const u16* Bb = BsB + RB * 16384;
  const int nt4 = nt * 4;
  bf16x8 a0[4][2], a1[4][2], b0[2][2], b1[2][2];

#pragma unroll
  for (int mf = 0; mf < 4; ++mf)
#pragma unroll
    for (int kk = 0; kk < 2; ++kk)
      a0[mf][kk] = frag_ld(Ab, wr * 128 + mf * 16 + row16, kk * 4 + quad);
#pragma unroll
  for (int nf = 0; nf < 2; ++nf)
#pragma unroll
    for (int kk = 0; kk < 2; ++kk)
      b0[nf][kk] = frag_ld(Bb, wc * 64 + nf * 16 + row16, kk * 4 + quad);
  stage_half(4 * k + 5, nt4, A, B, K, m0, n0, AsB, BsB, w, rowin, colsw);
  SBAR0(); HWBAR(); SBAR0();
  __builtin_amdgcn_s_setprio(1);
#pragma unroll
  for (int mf = 0; mf < 4; ++mf)
#pragma unroll
    for (int nf = 0; nf < 2; ++nf)
#pragma unroll
      for (int kk = 0; kk < 2; ++kk)
        acc[mf][nf] = __builtin_amdgcn_mfma_f32_16x16x32_bf16(a0[mf][kk], b0[nf][kk], acc[mf][nf], 0, 0, 0);
  __builtin_amdgcn_s_setprio(0);
  SBAR0(); HWBAR(); SBAR0();

#pragma unroll
  for (int nf = 0; nf < 2; ++nf)
#pragma unroll
    for (int kk = 0; kk < 2; ++kk)
      b1[nf][kk] = frag_ld(Bb, wc * 64 + 32 + nf * 16 + row16, kk * 4 + quad);
  stage_half(4 * k + 6, nt4, A, B, K, m0, n0, AsB, BsB, w, rowin, colsw);
  SBAR0(); HWBAR(); SBAR0();
  __builtin_amdgcn_s_setprio(1);
#pragma unroll
  for (int mf = 0; mf < 4; ++mf)
#pragma unroll
    for (int nf = 0; nf < 2; ++nf)
#pragma unroll
      for (int kk = 0; kk < 2; ++kk)
        acc[mf][2 + nf] = __builtin_amdgcn_mfma_f32_16x16x32_bf16(a0[mf][kk], b1[nf][kk], acc[mf][2 + nf], 0, 0, 0);
  __builtin_amdgcn_s_setprio(0);
  SBAR0(); HWBAR(); SBAR0();

#pragma unroll
  for (int mf = 0; mf < 4; ++mf)
#pragma unroll
    for (int kk = 0; kk < 2; ++kk)
      a1[mf][kk] = frag_ld(Ab, wr * 128 + 64 + mf * 16 + row16, kk * 4 + quad);
  stage_half(4 * k + 7, nt4, A, B, K, m0, n0, AsB, BsB, w, rowin, colsw);
  SBAR0(); HWBAR(); SBAR0();
  __builtin_amdgcn_s_setprio(1);
#pragma unroll
  for (int mf = 0; mf < 4; ++mf)
#pragma unroll
    for (int nf = 0; nf < 2; ++nf)
#pragma unroll
      for (int kk = 0; kk < 2; ++kk)
        acc[4 + mf][nf] = __builtin_amdgcn_mfma_f32_16x16x32_bf16(a1[mf][kk], b0[nf][kk], acc[4 + mf][nf], 0, 0, 0);
  __builtin_amdgcn_s_setprio(0);
  SBAR0(); HWBAR(); SBAR0();

  stage_half(4 * k + 8, nt4, A, B, K, m0, n0, AsB, BsB, w, rowin, colsw);
  SBAR0();
  if (k < nt - 2) { asm volatile("s_waitcnt vmcnt(2)" ::: "memory"); }
  else            { asm volatile("s_waitcnt vmcnt(0)" ::: "memory"); }
  HWBAR(); SBAR0();
  __builtin_amdgcn_s_setprio(1);
#pragma unroll
  for (int mf = 0; mf < 4; ++mf)
#pragma unroll
    for (int nf = 0; nf < 2; ++nf)
#pragma unroll
      for (int kk = 0; kk < 2; ++kk)
        acc[4 + mf][2 + nf] = __builtin_amdgcn_mfma_f32_16x16x32_bf16(a1[mf][kk], b1[nf][kk], acc[4 + mf][2 + nf], 0, 0, 0);
  __builtin_amdgcn_s_setprio(0);
  SBAR0(); HWBAR(); SBAR0();
}

__global__ __launch_bounds__(512, 2) void k_gemm256(
    const u16* __restrict__ A, const u16* __restrict__ B, float* __restrict__ C,
    int M, int N, int K) {
  __shared__ u16 As[2 * 16384];
  __shared__ u16 Bs[2 * 16384];

  const int tid   = threadIdx.x;
  const int lane  = tid & 63;
  const int w     = tid >> 6;
  const int wr    = w >> 2;
  const int wc    = w & 3;
  const int row16 = lane & 15;
  const int quad  = lane >> 4;
  const int rowin = lane >> 3;
  const int colsw = ((lane & 7) ^ (lane >> 3)) << 3;

  const int nwg = (int)gridDim.x;
  const int bid = (int)blockIdx.x;
  const int xcd = bid & 7, rest = bid >> 3;
  const int qq = nwg >> 3, rr = nwg & 7;
  const int wg = (xcd < rr ? xcd * (qq + 1) : rr * (qq + 1) + (xcd - rr) * qq) + rest;
  const int nbx = N >> 8;
  const int m0 = (wg / nbx) << 8;
  const int n0 = (wg % nbx) << 8;

  const int nt = K >> 6;
  f32x4 acc[8][4] = {};

#pragma unroll
  for (int H = 0; H < 5; ++H)
    stage_half(H, nt * 4, A, B, K, m0, n0, As, Bs, w, rowin, colsw);
  asm volatile("s_waitcnt vmcnt(2)" ::: "memory");
  HWBAR(); SBAR0();

  int k = 0;
  for (; k + 1 < nt; k += 2) {
    gemm256_group<0>(k,     nt, A, B, K, m0, n0, As, Bs, wr, wc, row16, quad, w, rowin, colsw, acc);
    gemm256_group<1>(k + 1, nt, A, B, K, m0, n0, As, Bs, wr, wc, row16, quad, w, rowin, colsw, acc);
  }
  if (k < nt)
    gemm256_group<0>(k, nt, A, B, K, m0, n0, As, Bs, wr, wc, row16, quad, w, rowin, colsw, acc);

#pragma unroll
  for (int mi = 0; mi < 8; ++mi) {
    const int gm = m0 + wr * 128 + mi * 16 + quad * 4;
#pragma unroll
    for (int nj = 0; nj < 4; ++nj) {
      const int gn = n0 + wc * 64 + nj * 16 + row16;
#pragma unroll
      for (int r = 0; r < 4; ++r)
        C[(size_t)(gm + r) * N + gn] = acc[mi][nj][r];
    }
  }
}

// ---------------- RoPE cos/sin table ----------------
__global__ void k_rope_tab(const int* __restrict__ pos_ids, float* __restrict__ tab) {
  const int t = threadIdx.x;
  const int r = blockIdx.x * 4 + t / 48;
  const int j = t % 48;
  const float pos = (float)pos_ids[r];
  float invf = powf(10000.0f, -(float)j * (1.0f / 48.0f));
  float e = pos * invf;
  tab[(size_t)r * 96 + j]      = cosf(e);
  tab[(size_t)r * 96 + 48 + j] = sinf(e);
}

// ---------------- RoPE + split q,k ----------------
__global__ void k_rope_split(const float* __restrict__ qkv, const float* __restrict__ tab,
                             u16* __restrict__ qb, u16* __restrict__ kb) {
  const int r  = blockIdx.x;
  const int hh = blockIdx.y;
  const int d  = threadIdx.x;
  const float* src;
  if (hh < 24) src = qkv + (size_t)r * 5120 + hh * 128;
  else         src = qkv + (size_t)r * 5120 + 3072 + (hh - 24) * 128;
  float x = src[d];
  float outv;
  if (d >= 96) {
    outv = x;
  } else {
    int j = (d < 48) ? d : d - 48;
    float c  = tab[(size_t)r * 96 + j];
    float sn = tab[(size_t)r * 96 + 48 + j];
    if (d < 48) outv = x * c - src[d + 48] * sn;
    else        outv = x * c + src[d - 48] * sn;
  }
  u16 o = f2bf(outv);
  if (hh < 24) qb[((size_t)r * 24 + hh) * 128 + d] = o;
  else         kb[((size_t)r * 8 + (hh - 24)) * 128 + d] = o;
}

// ---------------- V transpose ----------------
__global__ void k_vtrans(const float* __restrict__ qkv, u16* __restrict__ vtg) {
  const int d  = threadIdx.x;
  const int kg = blockIdx.x;
  const int bk = blockIdx.y;
  const int b = bk >> 3, kvh = bk & 7;
  const float* src = qkv + (size_t)(b * 2048 + kg * 8) * 5120 + 4096 + kvh * 128 + d;
  u16x8 pack;
#pragma unroll
  for (int t = 0; t < 8; ++t) pack[t] = f2bf(src[(size_t)t * 5120]);
  *(u16x8*)(vtg + ((size_t)bk * 128 + d) * 2048 + kg * 8) = pack;
}

// ---------------- MFMA flash attention (causal, GQA 24q/8kv, D=128) ----------------
// 8 waves, 128 q rows/block. Swapped QK^T (in-lane softmax). All LDS XOR-swizzled
// at 16B granularity (byte ^= (row&7)<<4): Ks[64][128], Vt[128][64], Ps[128][64].
// T14 async-stage via regs. Output row stride 3328 (concat layout for Wo GEMM).
__global__ __launch_bounds__(512) void k_attn_mfma(
    const u16* __restrict__ qb, const u16* __restrict__ kb, const u16* __restrict__ vtg,
    u16* __restrict__ attnw) {
  __shared__ u16 Ks[64 * 128];
  __shared__ u16 Vt[128 * 64];
  __shared__ u16 Ps[128 * 64];

  const int tid   = threadIdx.x;
  const int lane  = tid & 63;
  const int w     = tid >> 6;      // 0..7
  const int row16 = lane & 15;
  const int quad  = lane >> 4;
  const int qt  = (int)gridDim.x - 1 - (int)blockIdx.x;  // heavy tiles first
  const int bh  = blockIdx.y;
  const int b   = bh / 24;
  const int h   = bh % 24;
  const int kvh = h / 3;
  const int q0  = qt * 128;
  const int qrow = q0 + w * 16 + row16;

  const u16* qbase = qb + (((size_t)(b * 2048 + qrow)) * 24 + h) * 128;
  bf16x8 qfrag[4];
#pragma unroll
  for (int kk = 0; kk < 4; ++kk) qfrag[kk] = *(const bf16x8*)(qbase + kk * 32 + quad * 8);

  const u16* kbbase = kb + ((size_t)(b * 2048) * 8 + kvh) * 128;
  const u16* vtbase = vtg + (size_t)(b * 8 + kvh) * 128 * 2048;

  f32x4 o[8] = {};
  float m_st = -INFINITY;
  float l_st = 0.f;
  const float C1 = 0.08838834764831845f * 1.4426950408889634f;  // SCALE * log2(e)

  const int ntile = 2 * qt + 2;

  // T14 prologue: tile 0 into regs
  u16x8 kr[2], vr[2];
#pragma unroll
  for (int i = 0; i < 2; ++i) {
    int c = tid + i * 512;
    kr[i] = *(const u16x8*)(kbbase + (size_t)(c >> 4) * 1024 + (c & 15) * 8);
  }
#pragma unroll
  for (int i = 0; i < 2; ++i) {
    int c = tid + i * 512;
    vr[i] = *(const u16x8*)(vtbase + (size_t)(c >> 3) * 2048 + (c & 7) * 8);
  }

  for (int t = 0; t < ntile; ++t) {
    const int kb0 = t * 64;
    __syncthreads();  // previous tile fully consumed
    // staged regs -> swizzled LDS
#pragma unroll
    for (int i = 0; i < 2; ++i) {
      int c = tid + i * 512;
      int kk = c >> 4;
      int slot = (c & 15) ^ (kk & 7);
      *(u16x8*)&Ks[kk * 128 + slot * 8] = kr[i];
    }
#pragma unroll
    for (int i = 0; i < 2; ++i) {
      int c = tid + i * 512;
      int d = c >> 3;
      int slot = (c & 7) ^ (d & 7);
      *(u16x8*)&Vt[d * 64 + slot * 8] = vr[i];
    }
    __syncthreads();  // tile resident
    // issue next-tile loads; latency hides under compute
    if (t + 1 < ntile) {
      const int nb0 = kb0 + 64;
#pragma unroll
      for (int i = 0; i < 2; ++i) {
        int c = tid + i * 512;
        kr[i] = *(const u16x8*)(kbbase + (size_t)(nb0 + (c >> 4)) * 1024 + (c & 15) * 8);
      }
#pragma unroll
      for (int i = 0; i < 2; ++i) {
        int c = tid + i * 512;
        vr[i] = *(const u16x8*)(vtbase + (size_t)(c >> 3) * 2048 + nb0 + (c & 7) * 8);
      }
    }

    // S^T = K Q^T (swapped): lane holds S[key=kb0+nt*16+quad*4+r][q=qrow]
    f32x4 s[4] = {};
    __builtin_amdgcn_s_setprio(1);
#pragma unroll
    for (int kk = 0; kk < 4; ++kk) {
#pragma unroll
      for (int nt = 0; nt < 4; ++nt) {
        int krow = nt * 16 + row16;
        bf16x8 kfr = *(const bf16x8*)&Ks[krow * 128 + (((kk * 4 + quad) ^ (krow & 7)) << 3)];
        s[nt] = __builtin_amdgcn_mfma_f32_16x16x32_bf16(kfr, qfrag[kk], s[nt], 0, 0, 0);
      }
    }
    __builtin_amdgcn_s_setprio(0);

    // causal mask on the last two tiles (vacuous for upper waves)
    if (t >= 2 * qt) {
#pragma unroll
      for (int nt = 0; nt < 4; ++nt) {
        int kbase = kb0 + nt * 16 + quad * 4;
#pragma unroll
        for (int r = 0; r < 4; ++r)
          if (kbase + r > qrow) s[nt][r] = -INFINITY;
      }
    }

    // online softmax: in-lane over 16 keys + 2 cross-quad reduces
    float mx = s[0][0];
#pragma unroll
    for (int nt = 0; nt < 4; ++nt)
#pragma unroll
      for (int r = 0; r < 4; ++r) mx = fmaxf(mx, s[nt][r]);
    mx = fmaxf(mx, __shfl_xor(mx, 16));
    mx = fmaxf(mx, __shfl_xor(mx, 32));
    float mnew = fmaxf(m_st, mx);
    float alpha = fast_exp2((m_st - mnew) * C1);
    m_st = mnew;
    float rs = 0.f;
#pragma unroll
    for (int nt = 0; nt < 4; ++nt)
#pragma unroll
      for (int r = 0; r < 4; ++r) {
        float p = fast_exp2((s[nt][r] - mnew) * C1);
        s[nt][r] = p;
        rs += p;
      }
    rs += __shfl_xor(rs, 16);
    rs += __shfl_xor(rs, 32);
    l_st = l_st * alpha + rs;
#pragma unroll
    for (int r = 0; r < 4; ++r) {
      float ar = __shfl(alpha, quad * 4 + r, 64);
#pragma unroll
      for (int dt = 0; dt < 8; ++dt) o[dt][r] *= ar;
    }

    // P^T -> Ps[q][key] (swizzled); wave-local region rows w*16..w*16+15
#pragma unroll
    for (int nt = 0; nt < 4; ++nt)
#pragma unroll
      for (int r = 0; r < 4; ++r) {
        int col = nt * 16 + quad * 4 + r;
        int slot = (col >> 3) ^ (row16 & 7);
        Ps[(w * 16 + row16) * 64 + slot * 8 + (col & 7)] = f2bf(s[nt][r]);
      }
    // wave-synchronous: same wave writes and reads its own Ps rows

    // O += P V
    __builtin_amdgcn_s_setprio(1);
#pragma unroll
    for (int kk2 = 0; kk2 < 2; ++kk2) {
      bf16x8 pa = *(const bf16x8*)&Ps[(w * 16 + row16) * 64 + (((kk2 * 4 + quad) ^ (row16 & 7)) << 3)];
#pragma unroll
      for (int dt = 0; dt < 8; ++dt) {
        int vrow = dt * 16 + row16;
        bf16x8 vfr = *(const bf16x8*)&Vt[vrow * 64 + (((kk2 * 4 + quad) ^ (vrow & 7)) << 3)];
        o[dt] = __builtin_amdgcn_mfma_f32_16x16x32_bf16(pa, vfr, o[dt], 0, 0, 0);
      }
    }
    __builtin_amdgcn_s_setprio(0);
  }

  // epilogue: normalize; write into concat layout (row stride 3328)
#pragma unroll
  for (int r = 0; r < 4; ++r) {
    float lq = __shfl(l_st, quad * 4 + r, 64);
    float inv = 1.0f / lq;
    int row = q0 + w * 16 + quad * 4 + r;
    size_t obase = ((size_t)(b * 2048 + row)) * 3328 + (size_t)h * 128;
#pragma unroll
    for (int dt = 0; dt < 8; ++dt)
      attnw[obase + dt * 16 + row16] = f2bf(o[dt][r] * inv);
  }
}

// ---------------- workspace layout (bytes), total 173,015,040 ----------------
#define OFF_XW    ((size_t)0)                     // [4096][3328] bf16 = 27262976
#define OFF_WWQ   ((size_t)27262976)              // [5120][3328] bf16 = 34078720 (Wqkv|Bqkv)
#define OFF_AQKVB ((size_t)61341696)              // [256][3072] bf16 = 1572864
#define OFF_WWO   ((size_t)62914560)              // [3072][3328] bf16 = 20447232 (Wo|Bo)
#define OFF_AOB   ((size_t)83361792)              // [256][3072] bf16 = 1572864
#define OFF_QKV   ((size_t)84934656)              // [4096][5120] f32 = 83886080
#define OFF_TA    ((size_t)168820736)             // [4096][256] f32 = 4194304
// overlays:
#define OFF_TA4   OFF_QKV                         // 4 slabs [4096][256] f32 = 16777216 (pre-qkv)
#define OFF_QB    OFF_XW                          // 25165824 <= 27262976 (post-qkv GEMM)
#define OFF_KB    OFF_WWQ                         // 8388608
#define OFF_VTG   (OFF_WWQ + (size_t)8388608)     // 8388608
#define OFF_RTAB  (OFF_WWQ + (size_t)16777216)    // 1572864
#define OFF_ATTNW OFF_QKV                         // [4096][3328] bf16 = 27262976 (post rope/vtrans)
#define OFF_TO4   (OFF_QKV + (size_t)27262976)    // 4 slabs [4096][256] f32 = 16777216

extern "C" void kernel_launch(void* const* d_in, const int* in_sizes, int n_in,
                              void* d_out, int out_size, void* d_ws, size_t ws_size,
                              hipStream_t stream) {
  const float* x    = (const float*)d_in[0];
  const float* Wqkv = (const float*)d_in[1];
  const float* Aqkv = (const float*)d_in[2];
  const float* Bqkv = (const float*)d_in[3];
  const float* Wo   = (const float*)d_in[4];
  const float* Ao   = (const float*)d_in[5];
  const float* Bo   = (const float*)d_in[6];
  const int*   pos  = (const int*)d_in[7];
  float* out = (float*)d_out;
  char* ws = (char*)d_ws;

  u16* xw    = (u16*)(ws + OFF_XW);
  u16* wwq   = (u16*)(ws + OFF_WWQ);
  u16* aqkvb = (u16*)(ws + OFF_AQKVB);
  u16* wwo   = (u16*)(ws + OFF_WWO);
  u16* aob   = (u16*)(ws + OFF_AOB);
  float* qkv = (float*)(ws + OFF_QKV);
  float* tA  = (float*)(ws + OFF_TA);  // (unused scratch, kept for layout stability)
  (void)tA;
  float* tA4 = (float*)(ws + OFF_TA4);
  u16* qb    = (u16*)(ws + OFF_QB);
  u16* kb    = (u16*)(ws + OFF_KB);
  u16* vtg   = (u16*)(ws + OFF_VTG);
  float* rtab = (float*)(ws + OFF_RTAB);
  u16* attnw = (u16*)(ws + OFF_ATTNW);
  float* tO4 = (float*)(ws + OFF_TO4);

  // 1) casts into concat layouts
  k_cast_str<<<dim3(3, 4096), 128, 0, stream>>>(x,    xw,  384, 3328, 0,    1.f);
  k_cast_str<<<dim3(3, 5120), 128, 0, stream>>>(Wqkv, wwq, 384, 3328, 0,    1.f);
  k_cast_str<<<dim3(1, 5120), 128, 0, stream>>>(Bqkv, wwq,  32, 3328, 3072, 1.f);
  k_cast_str<<<dim3(3, 256),  128, 0, stream>>>(Aqkv, aqkvb, 384, 3072, 0,  1.f);
  k_cast_str<<<dim3(3, 3072), 128, 0, stream>>>(Wo,   wwo, 384, 3328, 0,    1.f);
  k_cast_str<<<dim3(1, 3072), 128, 0, stream>>>(Bo,   wwo,  32, 3328, 3072, 1.f);
  k_cast_str<<<dim3(3, 256),  128, 0, stream>>>(Ao,   aob, 384, 3072, 0,    1.f);

  // 2) LoRA-A: tA = x @ Aqkv^T (split-K x4) -> xw tail (scaled by 2)
  k_gemm_bt_sk<<<dim3(4, 64, 4), 256, 0, stream>>>(xw, aqkvb, tA4, 4096, 256, 3328, 3072, 768);
  k_red4_cast<<<dim3(1, 4096), 64, 0, stream>>>(tA4, xw, 32, 3328, 3072, 2.f, (size_t)4096 * 256);

  // 3) qkv = [x | 2 tA] @ [Wqkv | Bqkv]^T  (K=3328)
  k_gemm256<<<dim3((5120 / 256) * (4096 / 256)), 512, 0, stream>>>(xw, wwq, qkv, 4096, 5120, 3328);

  // 4) rope table (wwq tail free) ; rope+split q,k ; transpose-cast v
  k_rope_tab<<<dim3(1024), 192, 0, stream>>>(pos, rtab);
  k_rope_split<<<dim3(4096, 32), 128, 0, stream>>>(qkv, rtab, qb, kb);
  k_vtrans<<<dim3(256, 16), 128, 0, stream>>>(qkv, vtg);

  // 5) MFMA flash attention -> attnw (stride 3328)
  k_attn_mfma<<<dim3(16, 48), 512, 0, stream>>>(qb, kb, vtg, attnw);

  // 6) LoRA-A out: tO = attn @ Ao^T (split-K x4) -> attnw tail (scaled by 2)
  k_gemm_bt_sk<<<dim3(4, 64, 4), 256, 0, stream>>>(attnw, aob, tO4, 4096, 256, 3328, 3072, 768);
  k_red4_cast<<<dim3(1, 4096), 64, 0, stream>>>(tO4, attnw, 32, 3328, 3072, 2.f, (size_t)4096 * 256);

  // 7) out = [attn | 2 tO] @ [Wo | Bo]^T  (K=3328)
  k_gemm256<<<dim3((3072 / 256) * (4096 / 256)), 512, 0, stream>>>(attnw, wwo, out, 4096, 3072, 3328);
}

// Round 5
// 734.451 us; speedup vs baseline: 1.4747x; 1.0025x over previous
//
#include <hip/hip_runtime.h>

typedef unsigned short u16;
typedef unsigned int   u32;

typedef __bf16 bf16_t;
typedef bf16_t bf16x8 __attribute__((ext_vector_type(8)));
typedef float  f32x4  __attribute__((ext_vector_type(4)));
typedef float  f32x16 __attribute__((ext_vector_type(16)));
typedef u16    u16x8  __attribute__((ext_vector_type(8)));
typedef u32    u32x4  __attribute__((ext_vector_type(4)));

__device__ __forceinline__ float bf2f(u16 u) { return __uint_as_float(((u32)u) << 16); }
__device__ __forceinline__ u16 f2bf(float f) {
  u32 u = __float_as_uint(f);
  u32 r = u + 0x7fffu + ((u >> 16) & 1u);
  return (u16)(r >> 16);
}
__device__ __forceinline__ float fast_exp2(float x) { return __builtin_amdgcn_exp2f(x); }

__device__ __forceinline__ void gload_lds16(const u16* g, u16* l) {
  __builtin_amdgcn_global_load_lds(
      (const __attribute__((address_space(1))) void*)g,
      (__attribute__((address_space(3))) void*)l,
      16, 0, 0);
}

#define SBAR0() __builtin_amdgcn_sched_barrier(0)
#define HWBAR() __builtin_amdgcn_s_barrier()

// ---------------- strided cast f32 -> bf16 (8 elems/thread, optional scale) ----------------
__global__ void k_cast_str(const float* __restrict__ in, u16* __restrict__ out,
                           int C8, int L, int off, float scale) {
  const int r  = blockIdx.y;
  const int c8 = blockIdx.x * 128 + threadIdx.x;
  if (c8 >= C8) return;
  const f32x4* p = (const f32x4*)(in + (size_t)r * (C8 * 8) + c8 * 8);
  f32x4 a = p[0], b = p[1];
  u16x8 o;
  o[0] = f2bf(a[0] * scale); o[1] = f2bf(a[1] * scale);
  o[2] = f2bf(a[2] * scale); o[3] = f2bf(a[3] * scale);
  o[4] = f2bf(b[0] * scale); o[5] = f2bf(b[1] * scale);
  o[6] = f2bf(b[2] * scale); o[7] = f2bf(b[3] * scale);
  *(u16x8*)(out + (size_t)r * L + off + c8 * 8) = o;
}

// ---------------- reduce 4 f32 slabs + scale + strided cast to bf16 ----------------
__global__ void k_red4_cast(const float* __restrict__ t4, u16* __restrict__ out,
                            int C8, int L, int off, float scale, size_t plane) {
  const int r  = blockIdx.y;
  const int c8 = blockIdx.x * 64 + threadIdx.x;
  if (c8 >= C8) return;
  size_t base = (size_t)r * (C8 * 8) + c8 * 8;
  float s[8];
#pragma unroll
  for (int j = 0; j < 8; ++j) s[j] = 0.f;
#pragma unroll
  for (int p = 0; p < 4; ++p) {
    const f32x4* q = (const f32x4*)(t4 + p * plane + base);
    f32x4 a = q[0], b = q[1];
    s[0] += a[0]; s[1] += a[1]; s[2] += a[2]; s[3] += a[3];
    s[4] += b[0]; s[5] += b[1]; s[6] += b[2]; s[7] += b[3];
  }
  u16x8 o;
#pragma unroll
  for (int j = 0; j < 8; ++j) o[j] = f2bf(s[j] * scale);
  *(u16x8*)(out + (size_t)r * L + off + c8 * 8) = o;
}

// ---------------- small GEMM (64x64 tile), split-K slabs ----------------
__global__ __launch_bounds__(256) void k_gemm_bt_sk(
    const u16* __restrict__ A, const u16* __restrict__ B, float* __restrict__ C,
    int M, int N, int lda, int ldb, int kc) {
  __shared__ u16 As[64][64 + 8];
  __shared__ u16 Bs[64][64 + 8];
  const int tid   = threadIdx.x;
  const int lane  = tid & 63;
  const int w     = tid >> 6;
  const int wm    = (w >> 1) * 32;
  const int wn    = (w & 1) * 32;
  const int row16 = lane & 15;
  const int quad  = lane >> 4;
  const int m0 = blockIdx.y * 64;
  const int n0 = blockIdx.x * 64;
  const int ldr = tid >> 2;
  const int ldc = (tid & 3) * 16;
  const int z   = blockIdx.z;
  float* Cz = C + (size_t)z * M * N;
  const int kbeg = z * kc, kend = kbeg + kc;

  f32x4 acc[2][2] = {};

  for (int k0 = kbeg; k0 < kend; k0 += 64) {
    const u16* ga = A + (size_t)(m0 + ldr) * lda + (k0 + ldc);
    const u16* gb = B + (size_t)(n0 + ldr) * ldb + (k0 + ldc);
    u16x8 a0 = *(const u16x8*)ga;
    u16x8 a1 = *(const u16x8*)(ga + 8);
    u16x8 b0 = *(const u16x8*)gb;
    u16x8 b1 = *(const u16x8*)(gb + 8);
    __syncthreads();
    *(u16x8*)&As[ldr][ldc]     = a0;
    *(u16x8*)&As[ldr][ldc + 8] = a1;
    *(u16x8*)&Bs[ldr][ldc]     = b0;
    *(u16x8*)&Bs[ldr][ldc + 8] = b1;
    __syncthreads();
#pragma unroll
    for (int kk = 0; kk < 64; kk += 32) {
      bf16x8 af0 = *(const bf16x8*)&As[wm + row16][kk + quad * 8];
      bf16x8 af1 = *(const bf16x8*)&As[wm + 16 + row16][kk + quad * 8];
      bf16x8 bg0 = *(const bf16x8*)&Bs[wn + row16][kk + quad * 8];
      bf16x8 bg1 = *(const bf16x8*)&Bs[wn + 16 + row16][kk + quad * 8];
      acc[0][0] = __builtin_amdgcn_mfma_f32_16x16x32_bf16(af0, bg0, acc[0][0], 0, 0, 0);
      acc[0][1] = __builtin_amdgcn_mfma_f32_16x16x32_bf16(af0, bg1, acc[0][1], 0, 0, 0);
      acc[1][0] = __builtin_amdgcn_mfma_f32_16x16x32_bf16(af1, bg0, acc[1][0], 0, 0, 0);
      acc[1][1] = __builtin_amdgcn_mfma_f32_16x16x32_bf16(af1, bg1, acc[1][1], 0, 0, 0);
    }
  }
#pragma unroll
  for (int tm = 0; tm < 2; ++tm)
#pragma unroll
    for (int tn = 0; tn < 2; ++tn) {
      int gm = m0 + wm + tm * 16 + quad * 4;
      int gn = n0 + wn + tn * 16 + row16;
#pragma unroll
      for (int r = 0; r < 4; ++r)
        Cz[(size_t)(gm + r) * N + gn] = acc[tm][tn][r];
    }
}

// ================= 256x256 8-phase GEMM (m201 template, plain HIP) =================
__device__ __forceinline__ void stage_half(
    int H, int nt4,
    const u16* __restrict__ A, const u16* __restrict__ B, int K,
    int m0, int n0, u16* AsB, u16* BsB,
    int w, int rowin, int colsw) {
  if (H >= nt4) return;
  const int t = H >> 2, slot = H & 3;
  const int half = slot & 1;
  const u16* G = (slot < 2) ? A : B;
  const int r0 = (slot < 2) ? m0 : n0;
  u16* lds = ((slot < 2) ? AsB : BsB) + (t & 1) * 16384 + half * 8192;
  const int k0 = t * 64;
#pragma unroll
  for (int i = 0; i < 2; ++i) {
    const int chunk = w * 2 + i;
    const int row = half * 128 + chunk * 8 + rowin;
    gload_lds16(G + (size_t)(r0 + row) * K + k0 + colsw, lds + chunk * 512);
  }
}

__device__ __forceinline__ bf16x8 frag_ld(const u16* base, int row, int c16) {
  return *(const bf16x8*)(base + row * 64 + ((c16 ^ (row & 7)) << 3));
}

template <int RB>
__device__ __forceinline__ void gemm256_group(
    int k, int nt,
    const u16* __restrict__ A, const u16* __restrict__ B, int K,
    int m0, int n0, u16* AsB, u16* BsB,
    int wr, int wc, int row16, int quad, int w, int rowin, int colsw,
    f32x4 (&acc)[8][4]) {
  const u16* Ab = AsB + RB * 16384;
  const u16* Bb = BsB + RB * 16384;
  const int nt4 = nt * 4;
  bf16x8 a0[4][2], a1[4][2], b0[2][2], b1[2][2];

#pragma unroll
  for (int mf = 0; mf < 4; ++mf)
#pragma unroll
    for (int kk = 0; kk < 2; ++kk)
      a0[mf][kk] = frag_ld(Ab, wr * 128 + mf * 16 + row16, kk * 4 + quad);
#pragma unroll
  for (int nf = 0; nf < 2; ++nf)
#pragma unroll
    for (int kk = 0; kk < 2; ++kk)
      b0[nf][kk] = frag_ld(Bb, wc * 64 + nf * 16 + row16, kk * 4 + quad);
  stage_half(4 * k + 5, nt4, A, B, K, m0, n0, AsB, BsB, w, rowin, colsw);
  SBAR0(); HWBAR(); SBAR0();
  __builtin_amdgcn_s_setprio(1);
#pragma unroll
  for (int mf = 0; mf < 4; ++mf)
#pragma unroll
    for (int nf = 0; nf < 2; ++nf)
#pragma unroll
      for (int kk = 0; kk < 2; ++kk)
        acc[mf][nf] = __builtin_amdgcn_mfma_f32_16x16x32_bf16(a0[mf][kk], b0[nf][kk], acc[mf][nf], 0, 0, 0);
  __builtin_amdgcn_s_setprio(0);
  SBAR0(); HWBAR(); SBAR0();

#pragma unroll
  for (int nf = 0; nf < 2; ++nf)
#pragma unroll
    for (int kk = 0; kk < 2; ++kk)
      b1[nf][kk] = frag_ld(Bb, wc * 64 + 32 + nf * 16 + row16, kk * 4 + quad);
  stage_half(4 * k + 6, nt4, A, B, K, m0, n0, AsB, BsB, w, rowin, colsw);
  SBAR0(); HWBAR(); SBAR0();
  __builtin_amdgcn_s_setprio(1);
#pragma unroll
  for (int mf = 0; mf < 4; ++mf)
#pragma unroll
    for (int nf = 0; nf < 2; ++nf)
#pragma unroll
      for (int kk = 0; kk < 2; ++kk)
        acc[mf][2 + nf] = __builtin_amdgcn_mfma_f32_16x16x32_bf16(a0[mf][kk], b1[nf][kk], acc[mf][2 + nf], 0, 0, 0);
  __builtin_amdgcn_s_setprio(0);
  SBAR0(); HWBAR(); SBAR0();

#pragma unroll
  for (int mf = 0; mf < 4; ++mf)
#pragma unroll
    for (int kk = 0; kk < 2; ++kk)
      a1[mf][kk] = frag_ld(Ab, wr * 128 + 64 + mf * 16 + row16, kk * 4 + quad);
  stage_half(4 * k + 7, nt4, A, B, K, m0, n0, AsB, BsB, w, rowin, colsw);
  SBAR0(); HWBAR(); SBAR0();
  __builtin_amdgcn_s_setprio(1);
#pragma unroll
  for (int mf = 0; mf < 4; ++mf)
#pragma unroll
    for (int nf = 0; nf < 2; ++nf)
#pragma unroll
      for (int kk = 0; kk < 2; ++kk)
        acc[4 + mf][nf] = __builtin_amdgcn_mfma_f32_16x16x32_bf16(a1[mf][kk], b0[nf][kk], acc[4 + mf][nf], 0, 0, 0);
  __builtin_amdgcn_s_setprio(0);
  SBAR0(); HWBAR(); SBAR0();

  stage_half(4 * k + 8, nt4, A, B, K, m0, n0, AsB, BsB, w, rowin, colsw);
  SBAR0();
  if (k < nt - 2) { asm volatile("s_waitcnt vmcnt(2)" ::: "memory"); }
  else            { asm volatile("s_waitcnt vmcnt(0)" ::: "memory"); }
  HWBAR(); SBAR0();
  __builtin_amdgcn_s_setprio(1);
#pragma unroll
  for (int mf = 0; mf < 4; ++mf)
#pragma unroll
    for (int nf = 0; nf < 2; ++nf)
#pragma unroll
      for (int kk = 0; kk < 2; ++kk)
        acc[4 + mf][2 + nf] = __builtin_amdgcn_mfma_f32_16x16x32_bf16(a1[mf][kk], b1[nf][kk], acc[4 + mf][2 + nf], 0, 0, 0);
  __builtin_amdgcn_s_setprio(0);
  SBAR0(); HWBAR(); SBAR0();
}

__global__ __launch_bounds__(512, 2) void k_gemm256(
    const u16* __restrict__ A, const u16* __restrict__ B, float* __restrict__ C,
    int M, int N, int K) {
  __shared__ u16 As[2 * 16384];
  __shared__ u16 Bs[2 * 16384];

  const int tid   = threadIdx.x;
  const int lane  = tid & 63;
  const int w     = tid >> 6;
  const int wr    = w >> 2;
  const int wc    = w & 3;
  const int row16 = lane & 15;
  const int quad  = lane >> 4;
  const int rowin = lane >> 3;
  const int colsw = ((lane & 7) ^ (lane >> 3)) << 3;

  const int nwg = (int)gridDim.x;
  const int bid = (int)blockIdx.x;
  const int xcd = bid & 7, rest = bid >> 3;
  const int qq = nwg >> 3, rr = nwg & 7;
  const int wg = (xcd < rr ? xcd * (qq + 1) : rr * (qq + 1) + (xcd - rr) * qq) + rest;
  const int nbx = N >> 8;
  const int m0 = (wg / nbx) << 8;
  const int n0 = (wg % nbx) << 8;

  const int nt = K >> 6;
  f32x4 acc[8][4] = {};

#pragma unroll
  for (int H = 0; H < 5; ++H)
    stage_half(H, nt * 4, A, B, K, m0, n0, As, Bs, w, rowin, colsw);
  asm volatile("s_waitcnt vmcnt(2)" ::: "memory");
  HWBAR(); SBAR0();

  int k = 0;
  for (; k + 1 < nt; k += 2) {
    gemm256_group<0>(k,     nt, A, B, K, m0, n0, As, Bs, wr, wc, row16, quad, w, rowin, colsw, acc);
    gemm256_group<1>(k + 1, nt, A, B, K, m0, n0, As, Bs, wr, wc, row16, quad, w, rowin, colsw, acc);
  }
  if (k < nt)
    gemm256_group<0>(k, nt, A, B, K, m0, n0, As, Bs, wr, wc, row16, quad, w, rowin, colsw, acc);

#pragma unroll
  for (int mi = 0; mi < 8; ++mi) {
    const int gm = m0 + wr * 128 + mi * 16 + quad * 4;
#pragma unroll
    for (int nj = 0; nj < 4; ++nj) {
      const int gn = n0 + wc * 64 + nj * 16 + row16;
#pragma unroll
      for (int r = 0; r < 4; ++r)
        C[(size_t)(gm + r) * N + gn] = acc[mi][nj][r];
    }
  }
}

// ---------------- RoPE cos/sin table ----------------
__global__ void k_rope_tab(const int* __restrict__ pos_ids, float* __restrict__ tab) {
  const int t = threadIdx.x;
  const int r = blockIdx.x * 4 + t / 48;
  const int j = t % 48;
  const float pos = (float)pos_ids[r];
  float invf = powf(10000.0f, -(float)j * (1.0f / 48.0f));
  float e = pos * invf;
  tab[(size_t)r * 96 + j]      = cosf(e);
  tab[(size_t)r * 96 + 48 + j] = sinf(e);
}

// ---------------- RoPE + split q,k ----------------
__global__ void k_rope_split(const float* __restrict__ qkv, const float* __restrict__ tab,
                             u16* __restrict__ qb, u16* __restrict__ kb) {
  const int r  = blockIdx.x;
  const int hh = blockIdx.y;
  const int d  = threadIdx.x;
  const float* src;
  if (hh < 24) src = qkv + (size_t)r * 5120 + hh * 128;
  else         src = qkv + (size_t)r * 5120 + 3072 + (hh - 24) * 128;
  float x = src[d];
  float outv;
  if (d >= 96) {
    outv = x;
  } else {
    int j = (d < 48) ? d : d - 48;
    float c  = tab[(size_t)r * 96 + j];
    float sn = tab[(size_t)r * 96 + 48 + j];
    if (d < 48) outv = x * c - src[d + 48] * sn;
    else        outv = x * c + src[d - 48] * sn;
  }
  u16 o = f2bf(outv);
  if (hh < 24) qb[((size_t)r * 24 + hh) * 128 + d] = o;
  else         kb[((size_t)r * 8 + (hh - 24)) * 128 + d] = o;
}

// ---------------- V transpose ----------------
__global__ void k_vtrans(const float* __restrict__ qkv, u16* __restrict__ vtg) {
  const int d  = threadIdx.x;
  const int kg = blockIdx.x;
  const int bk = blockIdx.y;
  const int b = bk >> 3, kvh = bk & 7;
  const float* src = qkv + (size_t)(b * 2048 + kg * 8) * 5120 + 4096 + kvh * 128 + d;
  u16x8 pack;
#pragma unroll
  for (int t = 0; t < 8; ++t) pack[t] = f2bf(src[(size_t)t * 5120]);
  *(u16x8*)(vtg + ((size_t)bk * 128 + d) * 2048 + kg * 8) = pack;
}

// ---------------- MFMA flash attention, 32x32 structure (causal, GQA, D=128) ----------------
// 4 waves x 32 q-rows = 128 q/block. Swapped QK^T via mfma_32x32x16(K,Q) -> S^T with
// q = lane&31 for S, m, l, alpha AND O^T (no cross-lane alpha). Softmax: in-lane tree +
// one shfl_xor(32) each for max/sum. P->PV B-frags built in-register: cvt_pk + 4
// shfl_xor(32)/kt + selects. K/V staged by global_load_lds with pre-swizzled SOURCE
// (rule #21) into double-buffered LDS; one barrier per tile. T13 defer-max (THR=8).
// Fragment maps (m74/m101): C/D col=lane&31, row=(reg&3)+8*(reg>>2)+4*(lane>>5);
// A row=lane&31, k=(lane>>5)*8+j; B col=lane&31, k=(lane>>5)*8+j.
__global__ __launch_bounds__(256) void k_attn_mfma(
    const u16* __restrict__ qb, const u16* __restrict__ kb, const u16* __restrict__ vtg,
    u16* __restrict__ attnw) {
  __shared__ u16 KsA[8192], VtA[8192], KsB[8192], VtB[8192];

  const int tid  = threadIdx.x;
  const int lane = tid & 63;
  const int w    = tid >> 6;      // 0..3
  const int l31  = lane & 31;
  const int hi   = lane >> 5;
  const int r7   = lane & 7;
  const int qt   = (int)gridDim.x - 1 - (int)blockIdx.x;  // heavy tiles first
  const int bh   = blockIdx.y;
  const int b    = bh / 24;
  const int h    = bh % 24;
  const int kvh  = h / 3;
  const int q0   = qt * 128;
  const int qrow = q0 + w * 32 + l31;

  // Q fragments: Q[q=l31-row][k = 16kk + 8hi + j]
  const u16* qrb = qb + (((size_t)(b * 2048 + qrow)) * 24 + h) * 128;
  bf16x8 qf[8];
#pragma unroll
  for (int kk = 0; kk < 8; ++kk) qf[kk] = *(const bf16x8*)(qrb + kk * 16 + hi * 8);

  const u16* kbbase = kb + ((size_t)(b * 2048) * 8 + kvh) * 128;
  const u16* vtbase = vtg + (size_t)(b * 8 + kvh) * 128 * 2048;

  f32x16 o32[4] = {};
  float m_st = -INFINITY, l_st = 0.f;
  const float C1 = 0.08838834764831845f * 1.4426950408889634f;  // SCALE * log2(e)
  const int ntile = 2 * qt + 2;

  // stage one K/V tile (16KB each) into Kd/Vd; source col pre-swizzled so that
  // LDS(row, slot) = global(row, slot ^ (row&7)). Dest is wave-uniform (lane*16B HW).
#define STAGE(Kd, Vd, KB0)                                                          \
  {                                                                                 \
    _Pragma("unroll")                                                               \
    for (int i = 0; i < 4; ++i) {                                                   \
      const int c = w * 4 + i;                                                      \
      const int rowk = 4 * c + (lane >> 4);                                         \
      gload_lds16(kbbase + (size_t)((KB0) + rowk) * 1024 +                          \
                      (((lane & 15) ^ (rowk & 7)) << 3),                            \
                  (Kd) + c * 512);                                                  \
      const int rowv = 8 * c + (lane >> 3);                                         \
      gload_lds16(vtbase + (size_t)rowv * 2048 + (KB0) +                            \
                      (((lane & 7) ^ (rowv & 7)) << 3),                             \
                  (Vd) + c * 512);                                                  \
    }                                                                               \
  }

  STAGE(KsA, VtA, 0);
  __syncthreads();

  for (int t = 0; t < ntile; ++t) {
    const int kb0 = t * 64;
    const u16* Kc = (t & 1) ? KsB : KsA;
    const u16* Vc = (t & 1) ? VtB : VtA;
    if (t + 1 < ntile) {
      u16* Kn = (t & 1) ? KsA : KsB;
      u16* Vn = (t & 1) ? VtA : VtB;
      STAGE(Kn, Vn, kb0 + 64);
    }

    // S^T = K Q^T : s[kt] covers keys kb0+32kt+crow(reg,hi), q = l31
    f32x16 s[2] = {};
    __builtin_amdgcn_s_setprio(1);
#pragma unroll
    for (int kk = 0; kk < 8; ++kk) {
#pragma unroll
      for (int kt = 0; kt < 2; ++kt) {
        const int row = kt * 32 + l31;
        bf16x8 kf = *(const bf16x8*)&Kc[row * 128 + (((2 * kk + hi) ^ r7) << 3)];
        s[kt] = __builtin_amdgcn_mfma_f32_32x32x16_bf16(kf, qf[kk], s[kt], 0, 0, 0);
      }
    }
    __builtin_amdgcn_s_setprio(0);

    // causal mask (only the last two tiles have kb0 >= q0)
    if (kb0 >= q0) {
#pragma unroll
      for (int kt = 0; kt < 2; ++kt)
#pragma unroll
        for (int r = 0; r < 16; ++r) {
          const int key = kb0 + 32 * kt + (r & 3) + 8 * (r >> 2) + 4 * hi;
          if (key > qrow) s[kt][r] = -INFINITY;
        }
    }

    // ---- online softmax: in-lane tree + one shfl_xor(32) ----
    float tm[16];
#pragma unroll
    for (int r = 0; r < 16; ++r) tm[r] = fmaxf(s[0][r], s[1][r]);
#pragma unroll
    for (int st = 8; st >= 1; st >>= 1)
#pragma unroll
      for (int r = 0; r < 8; ++r)
        if (r < st) tm[r] = fmaxf(tm[r], tm[r + st]);
    float mx = fmaxf(tm[0], __shfl_xor(tm[0], 32));

    const bool skip = __all((mx - m_st) * C1 <= 8.0f);  // T13 defer-max
    if (!skip) {
      const float mnew = fmaxf(m_st, mx);
      const float alpha = fast_exp2((m_st - mnew) * C1);
      l_st *= alpha;
#pragma unroll
      for (int dt = 0; dt < 4; ++dt)
#pragma unroll
        for (int r = 0; r < 16; ++r) o32[dt][r] *= alpha;
      m_st = mnew;
    }
    const float mc = m_st * C1;
    float ts[16];
#pragma unroll
    for (int r = 0; r < 16; ++r) {
      float p0 = fast_exp2(__builtin_fmaf(s[0][r], C1, -mc));
      float p1 = fast_exp2(__builtin_fmaf(s[1][r], C1, -mc));
      s[0][r] = p0; s[1][r] = p1;
      ts[r] = p0 + p1;
    }
#pragma unroll
    for (int st = 8; st >= 1; st >>= 1)
#pragma unroll
      for (int r = 0; r < 8; ++r)
        if (r < st) ts[r] += ts[r + st];
    l_st += ts[0] + __shfl_xor(ts[0], 32);

    // ---- P -> PV B-fragments, in-register (per kt: 8 cvt_pk + 4 shfl_xor + selects) ----
    // pk[i] (hi=0 lane) = keys {2i',..} per crow map; exchange with lane^32 fills the
    // 8-consecutive-key words each B-frag needs: frag(ks) keys = 32kt+16ks+8hi+j.
    bf16x8 pb[4];
#pragma unroll
    for (int kt = 0; kt < 2; ++kt) {
      u32 pk[8];
#pragma unroll
      for (int i = 0; i < 8; ++i)
        asm("v_cvt_pk_bf16_f32 %0, %1, %2"
            : "=v"(pk[i]) : "v"(s[kt][2 * i]), "v"(s[kt][2 * i + 1]));
      u32 e0 = __shfl_xor(hi ? pk[0] : pk[2], 32);
      u32 e1 = __shfl_xor(hi ? pk[1] : pk[3], 32);
      u32 e2 = __shfl_xor(hi ? pk[4] : pk[6], 32);
      u32 e3 = __shfl_xor(hi ? pk[5] : pk[7], 32);
      u32x4 w0, w1;
      w0[0] = hi ? e0 : pk[0]; w0[1] = hi ? e1 : pk[1];
      w0[2] = hi ? pk[2] : e0; w0[3] = hi ? pk[3] : e1;
      w1[0] = hi ? e2 : pk[4]; w1[1] = hi ? e3 : pk[5];
      w1[2] = hi ? pk[6] : e2; w1[3] = hi ? pk[7] : e3;
      pb[2 * kt]     = __builtin_bit_cast(bf16x8, w0);
      pb[2 * kt + 1] = __builtin_bit_cast(bf16x8, w1);
    }

    // ---- O^T += V^T P^T : A=V^T[d=32dt+l31][key], B=P^T[key][q=l31] ----
    __builtin_amdgcn_s_setprio(1);
#pragma unroll
    for (int ks = 0; ks < 4; ++ks) {
#pragma unroll
      for (int dt = 0; dt < 4; ++dt) {
        const int vrow = dt * 32 + l31;
        bf16x8 vf = *(const bf16x8*)&Vc[vrow * 64 + (((2 * ks + hi) ^ r7) << 3)];
        o32[dt] = __builtin_amdgcn_mfma_f32_32x32x16_bf16(vf, pb[ks], o32[dt], 0, 0, 0);
      }
    }
    __builtin_amdgcn_s_setprio(0);

    __syncthreads();  // staged writes done (implicit vmcnt drain) + reads of Kc/Vc done
  }

  // ---- epilogue: normalize (l in-lane), transpose via per-wave swizzled LDS scratch ----
  const float inv = 1.0f / l_st;
  u16* scr = ((w < 2) ? KsA : VtA) + (w & 1) * 4096;  // 32 rows x 128 u16 per wave
#pragma unroll
  for (int dt = 0; dt < 4; ++dt)
#pragma unroll
    for (int r = 0; r < 16; ++r) {
      const int d = 32 * dt + (r & 3) + 8 * (r >> 2) + 4 * hi;
      const int slot = (d >> 3) ^ (l31 & 7);
      scr[l31 * 128 + slot * 8 + (d & 7)] = f2bf(o32[dt][r] * inv);
    }
  // wave-synchronous read-back, coalesced global store (2 lanes per q-row)
  const int q32r = lane >> 1, part = lane & 1;
  const size_t grow = ((size_t)(b * 2048 + q0 + w * 32 + q32r)) * 3328 + (size_t)h * 128;
#pragma unroll
  for (int c = 0; c < 8; ++c) {
    const int d0 = part * 64 + c * 8;
    const int s2 = (d0 >> 3) ^ (q32r & 7);
    *(u16x8*)(attnw + grow + d0) = *(const u16x8*)&scr[q32r * 128 + s2 * 8];
  }
}

// ---------------- workspace layout (bytes), total 173,015,040 ----------------
#define OFF_XW    ((size_t)0)
#define OFF_WWQ   ((size_t)27262976)
#define OFF_AQKVB ((size_t)61341696)
#define OFF_WWO   ((size_t)62914560)
#define OFF_AOB   ((size_t)83361792)
#define OFF_QKV   ((size_t)84934656)
#define OFF_TA    ((size_t)168820736)
#define OFF_TA4   OFF_QKV
#define OFF_QB    OFF_XW
#define OFF_KB    OFF_WWQ
#define OFF_VTG   (OFF_WWQ + (size_t)8388608)
#define OFF_RTAB  (OFF_WWQ + (size_t)16777216)
#define OFF_ATTNW OFF_QKV
#define OFF_TO4   (OFF_QKV + (size_t)27262976)

extern "C" void kernel_launch(void* const* d_in, const int* in_sizes, int n_in,
                              void* d_out, int out_size, void* d_ws, size_t ws_size,
                              hipStream_t stream) {
  const float* x    = (const float*)d_in[0];
  const float* Wqkv = (const float*)d_in[1];
  const float* Aqkv = (const float*)d_in[2];
  const float* Bqkv = (const float*)d_in[3];
  const float* Wo   = (const float*)d_in[4];
  const float* Ao   = (const float*)d_in[5];
  const float* Bo   = (const float*)d_in[6];
  const int*   pos  = (const int*)d_in[7];
  float* out = (float*)d_out;
  char* ws = (char*)d_ws;

  u16* xw    = (u16*)(ws + OFF_XW);
  u16* wwq   = (u16*)(ws + OFF_WWQ);
  u16* aqkvb = (u16*)(ws + OFF_AQKVB);
  u16* wwo   = (u16*)(ws + OFF_WWO);
  u16* aob   = (u16*)(ws + OFF_AOB);
  float* qkv = (float*)(ws + OFF_QKV);
  float* tA4 = (float*)(ws + OFF_TA4);
  u16* qb    = (u16*)(ws + OFF_QB);
  u16* kb    = (u16*)(ws + OFF_KB);
  u16* vtg   = (u16*)(ws + OFF_VTG);
  float* rtab = (float*)(ws + OFF_RTAB);
  u16* attnw = (u16*)(ws + OFF_ATTNW);
  float* tO4 = (float*)(ws + OFF_TO4);

  // 1) casts into concat layouts
  k_cast_str<<<dim3(3, 4096), 128, 0, stream>>>(x,    xw,  384, 3328, 0,    1.f);
  k_cast_str<<<dim3(3, 5120), 128, 0, stream>>>(Wqkv, wwq, 384, 3328, 0,    1.f);
  k_cast_str<<<dim3(1, 5120), 128, 0, stream>>>(Bqkv, wwq,  32, 3328, 3072, 1.f);
  k_cast_str<<<dim3(3, 256),  128, 0, stream>>>(Aqkv, aqkvb, 384, 3072, 0,  1.f);
  k_cast_str<<<dim3(3, 3072), 128, 0, stream>>>(Wo,   wwo, 384, 3328, 0,    1.f);
  k_cast_str<<<dim3(1, 3072), 128, 0, stream>>>(Bo,   wwo,  32, 3328, 3072, 1.f);
  k_cast_str<<<dim3(3, 256),  128, 0, stream>>>(Ao,   aob, 384, 3072, 0,    1.f);

  // 2) LoRA-A: tA = x @ Aqkv^T (split-K x4) -> xw tail (scaled by 2)
  k_gemm_bt_sk<<<dim3(4, 64, 4), 256, 0, stream>>>(xw, aqkvb, tA4, 4096, 256, 3328, 3072, 768);
  k_red4_cast<<<dim3(1, 4096), 64, 0, stream>>>(tA4, xw, 32, 3328, 3072, 2.f, (size_t)4096 * 256);

  // 3) qkv = [x | 2 tA] @ [Wqkv | Bqkv]^T  (K=3328)
  k_gemm256<<<dim3((5120 / 256) * (4096 / 256)), 512, 0, stream>>>(xw, wwq, qkv, 4096, 5120, 3328);

  // 4) rope table ; rope+split q,k ; transpose-cast v
  k_rope_tab<<<dim3(1024), 192, 0, stream>>>(pos, rtab);
  k_rope_split<<<dim3(4096, 32), 128, 0, stream>>>(qkv, rtab, qb, kb);
  k_vtrans<<<dim3(256, 16), 128, 0, stream>>>(qkv, vtg);

  // 5) MFMA flash attention -> attnw (stride 3328)
  k_attn_mfma<<<dim3(16, 48), 256, 0, stream>>>(qb, kb, vtg, attnw);

  // 6) LoRA-A out: tO = attn @ Ao^T (split-K x4) -> attnw tail (scaled by 2)
  k_gemm_bt_sk<<<dim3(4, 64, 4), 256, 0, stream>>>(attnw, aob, tO4, 4096, 256, 3328, 3072, 768);
  k_red4_cast<<<dim3(1, 4096), 64, 0, stream>>>(tO4, attnw, 32, 3328, 3072, 2.f, (size_t)4096 * 256);

  // 7) out = [attn | 2 tO] @ [Wo | Bo]^T  (K=3328)
  k_gemm256<<<dim3((3072 / 256) * (4096 / 256)), 512, 0, stream>>>(attnw, wwo, out, 4096, 3072, 3328);
}